// Round 9
// baseline (271.787 us; speedup 1.0000x reference)
//
#include <hip/hip_runtime.h>
#include <hip/hip_bf16.h>

typedef __attribute__((ext_vector_type(8))) short short8;
typedef __attribute__((ext_vector_type(4))) short short4v;
typedef __attribute__((ext_vector_type(4))) unsigned short ushort4v;
typedef __attribute__((ext_vector_type(4))) float f32x4;

#define NTOK 8192
#define DM 1024
#define DE 1024
#define NE 8

__device__ __forceinline__ float bf2f(unsigned short u) {
  union { unsigned int i; float f; } v; v.i = ((unsigned int)u) << 16; return v.f;
}
__device__ __forceinline__ unsigned short f2bf(float f) {
  union { float f; unsigned int i; } v; v.f = f;
  unsigned int lsb = (v.i >> 16) & 1;
  v.i += 0x7fffu + lsb;  // RNE; inputs finite
  return (unsigned short)(v.i >> 16);
}
__device__ __forceinline__ void gl_lds(const short* g, short* l) {
  __builtin_amdgcn_global_load_lds((const __attribute__((address_space(1))) void*)g,
                                   (__attribute__((address_space(3))) void*)l, 16, 0, 0);
}

// ------- W fp32 [K][N] -> bf16 transposed; W1/W3 interleaved into wcat -------
// wcat[e]: 2048 rows in 256-row groups: group g rows [g*256, g*256+128) = W1^T
//          cols g*128+[0,128); rows +128 = W3^T same cols.
// w2t[e]: plain W2^T [1024][1024]
__global__ __launch_bounds__(256) void k_transw(const float* __restrict__ W1,
                                                const float* __restrict__ W2,
                                                const float* __restrict__ W3,
                                                short* __restrict__ wcat,
                                                short* __restrict__ w2t) {
  __shared__ float t[64][65];
  int mid = blockIdx.z;
  const float* src;
  if (mid < 8)       src = W1 + (size_t)mid * (DM * DE);
  else if (mid < 16) src = W3 + (size_t)(mid - 8) * (DM * DE);
  else               src = W2 + (size_t)(mid - 16) * (DE * DM);
  int tid = threadIdx.x;
  int tr = tid >> 4, tc = tid & 15;
  int kbase = blockIdx.y * 64, nbase = blockIdx.x * 64;
#pragma unroll
  for (int j = 0; j < 4; j++) {
    int kr = tr + j * 16;
    f32x4 v = *(const f32x4*)(src + (size_t)(kbase + kr) * 1024 + nbase + tc * 4);
    t[kr][tc * 4 + 0] = v[0]; t[kr][tc * 4 + 1] = v[1];
    t[kr][tc * 4 + 2] = v[2]; t[kr][tc * 4 + 3] = v[3];
  }
  __syncthreads();
#pragma unroll
  for (int j = 0; j < 4; j++) {
    int n = tr + j * 16;          // source column (0..1023 within this matrix)
    int ng = nbase + n;
    short4v o;
    o[0] = (short)f2bf(t[tc * 4 + 0][n]);
    o[1] = (short)f2bf(t[tc * 4 + 1][n]);
    o[2] = (short)f2bf(t[tc * 4 + 2][n]);
    o[3] = (short)f2bf(t[tc * 4 + 3][n]);
    size_t dsto;
    if (mid < 16) {
      int e = mid & 7, p = mid >> 3;
      int row_out = ((ng >> 7) * 256) + p * 128 + (ng & 127);
      dsto = (size_t)e * (2048 * 1024) + (size_t)row_out * 1024 + kbase + tc * 4;
      *(short4v*)(wcat + dsto) = o;
    } else {
      int e = mid - 16;
      dsto = (size_t)e * (1024 * 1024) + (size_t)ng * 1024 + kbase + tc * 4;
      *(short4v*)(w2t + dsto) = o;
    }
  }
}

// ------- router: fp32 logits, softmax-top2, fused x->bf16 conversion -------
__global__ __launch_bounds__(256) void k_router(const float* __restrict__ x,
                                                const float* __restrict__ Wr,
                                                short* __restrict__ xb,
                                                int* __restrict__ esel,
                                                float* __restrict__ wgt) {
  int wid = threadIdx.x >> 6, lane = threadIdx.x & 63;
  int t = blockIdx.x * 4 + wid;
  const float* xr = x + (size_t)t * DM;
  float acc[8];
#pragma unroll
  for (int e = 0; e < 8; e++) acc[e] = 0.f;
#pragma unroll
  for (int i = 0; i < 4; i++) {
    int kb = (i * 64 + lane) * 4;
    f32x4 v = *(const f32x4*)(xr + kb);
    ushort4v ob;
#pragma unroll
    for (int j = 0; j < 4; j++) {
      f32x4 w0 = *(const f32x4*)(Wr + (size_t)(kb + j) * 8);
      f32x4 w1 = *(const f32x4*)(Wr + (size_t)(kb + j) * 8 + 4);
      float xv = v[j];
      ob[j] = f2bf(xv);
      acc[0] += xv * w0[0]; acc[1] += xv * w0[1];
      acc[2] += xv * w0[2]; acc[3] += xv * w0[3];
      acc[4] += xv * w1[0]; acc[5] += xv * w1[1];
      acc[6] += xv * w1[2]; acc[7] += xv * w1[3];
    }
    *(ushort4v*)(xb + (size_t)t * DM + kb) = ob;
  }
#pragma unroll
  for (int off = 32; off; off >>= 1)
#pragma unroll
    for (int e = 0; e < 8; e++) acc[e] += __shfl_xor(acc[e], off);
  float m0 = -1e30f, m1 = -1e30f; int e0 = 0, e1 = 0;
#pragma unroll
  for (int e = 0; e < 8; e++) {
    float v = acc[e];
    if (v > m0) { m1 = m0; e1 = e0; m0 = v; e0 = e; }
    else if (v > m1) { m1 = v; e1 = e; }
  }
  float p = __expf(m1 - m0);
  if (lane == 0) {
    esel[2 * t] = e0; esel[2 * t + 1] = e1;
    wgt[2 * t] = 1.f / (1.f + p); wgt[2 * t + 1] = p / (1.f + p);
  }
}

// ---- ranks via wave ballots + per-block aggregated atomics ----
__global__ __launch_bounds__(256) void k_rank(const int* __restrict__ esel,
                                              int* __restrict__ cnt,
                                              int* __restrict__ rank) {
  __shared__ int wcnt[4][8];
  __shared__ int woff[4][8];
  int tid = threadIdx.x;
  int lane = tid & 63, wid = tid >> 6;
  int t = blockIdx.x * 256 + tid;
  int e0 = esel[2 * t], e1 = esel[2 * t + 1];
  unsigned long long lt = (lane == 0) ? 0ull : ((~0ull) >> (64 - lane));
  int r0 = 0, r1 = 0;
#pragma unroll
  for (int e = 0; e < 8; e++) {
    unsigned long long m0 = __ballot(e0 == e);
    unsigned long long m1 = __ballot(e1 == e);
    int c0 = __popcll(m0);
    if (e0 == e) r0 = __popcll(m0 & lt);
    if (e1 == e) r1 = c0 + __popcll(m1 & lt);
    if (lane == 0) wcnt[wid][e] = c0 + __popcll(m1);
  }
  __syncthreads();
  if (tid < 8) {
    int e = tid;
    int c0 = wcnt[0][e], c1 = wcnt[1][e], c2 = wcnt[2][e], c3 = wcnt[3][e];
    int base = atomicAdd(&cnt[e], c0 + c1 + c2 + c3);
    woff[0][e] = base;
    woff[1][e] = base + c0;
    woff[2][e] = base + c0 + c1;
    woff[3][e] = base + c0 + c1 + c2;
  }
  __syncthreads();
  rank[2 * t] = woff[wid][e0] + r0;
  rank[2 * t + 1] = woff[wid][e1] + r1;
}

__global__ void k_offsets(const int* __restrict__ cnt, int* __restrict__ off) {
  if (threadIdx.x == 0) {
    int s = 0;
    for (int e = 0; e < NE; e++) { off[e] = s; s += cnt[e]; }
  }
}

__global__ __launch_bounds__(256) void k_scatter(const int* __restrict__ off,
                                                 const int* __restrict__ esel,
                                                 const int* __restrict__ rank,
                                                 int* __restrict__ tok_of_slot,
                                                 int* __restrict__ slot_of_tok) {
  int t = blockIdx.x * 256 + threadIdx.x;
#pragma unroll
  for (int j = 0; j < 2; j++) {
    int e = esel[2 * t + j];
    int s = off[e] + rank[2 * t + j];
    tok_of_slot[s] = t;
    slot_of_tok[2 * t + j] = s;
  }
}

// == 256x256-tile BK=64 grouped GEMM: R6 dataflow + m201 per-phase rhythm ==
// 1 block/CU, 8 waves = 2(M:wr stripes) x 4(N:wcn), acc[8][4] = 128 AGPR.
// LDS: A[2buf][2half][128][64] + B same = 128 KB; 16B-chunk swizzle c^(row&7)
// (verified conflict-free R5/R6); linear dest + inverse-swizzled source.
// Per K-tile: 4 phases, each the m201 rhythm:
//   {8|4 ds_reads  ||  stage 1 half-tile (2 gl_lds)}  ->  s_barrier
//   -> lgkmcnt(0) -> setprio(1) -> 16 MFMA -> setprio(0) -> s_barrier
// Stages (R6 liveness-verified): q0->B1(kt+1,buf^1), q1->A1(kt+1,buf^1),
// q2->A0(kt+2,buf), q3->B0(kt+2,buf). Counted waits (FIFO-derived, never 0):
// vmcnt(8) before q1's closing barrier (A1(kt+1) landed for q2's reads);
// vmcnt(6) before q3's closing barrier (A0,B0,B1(kt+1) landed for q0's reads).
// FFN1=1: A = xb gathered, B = wcat group (n-frags 0,1 = W1, 2,3 = W3 same
//         cols -> silu lane-local), epilogue -> h (128 cols/blk)
// FFN1=0: A = h (slot rows), B = w2t, epilogue -> y (256 cols/blk)
template<int FFN1>
__global__ __launch_bounds__(512, 2) void k_ffn(const short* __restrict__ Abase,
                                                const short* __restrict__ Bbase,
                                                const int* __restrict__ cnt,
                                                const int* __restrict__ off,
                                                const int* __restrict__ tok_of_slot,
                                                short* __restrict__ outp) {
  const int e = blockIdx.y;
  const int cnt_e = cnt[e];
  const int m0 = blockIdx.z * 256;
  if (m0 >= cnt_e) return;
  const int bse = off[e];
  const int nt = blockIdx.x;
  const short* Bt = Bbase + (size_t)e * ((FFN1 ? 2048 : 1024) * 1024) + (size_t)(nt * 256) * 1024;

  __shared__ __align__(128) short Al[2][16384];  // [half][128][64] x2buf = 64 KB
  __shared__ __align__(128) short Bl[2][16384];  // 64 KB (128 KB total)

  const int tid = threadIdx.x;
  const int lane = tid & 63, wid = tid >> 6;
  const int wr = wid >> 2, wcn = wid & 3;

  // staging sources (R6-verified): seg = wid*2+j, rows seg*8+(lane>>3) of half;
  // source chunk sc = (lane&7)^(lane>>3) (inverse swizzle; LDS linear)
  const int sc = ((lane & 7) ^ (lane >> 3)) * 8;
  const short* srcA[2][2];  // [j][h]
  const short* srcB[2];     // [j]; half via +131072
#pragma unroll
  for (int j = 0; j < 2; j++) {
#pragma unroll
    for (int h = 0; h < 2; h++) {
      int r = h * 128 + (wid * 2 + j) * 8 + (lane >> 3);
      int row = m0 + r; if (row >= cnt_e) row = cnt_e - 1;
      long ar = FFN1 ? (long)tok_of_slot[bse + row] : (long)(bse + row);
      srcA[j][h] = Abase + ar * 1024 + sc;
    }
    srcB[j] = Bt + (size_t)((wid * 2 + j) * 8 + (lane >> 3)) * 1024 + sc;
  }

  // fragment LDS byte offsets (R6-verified; ks1 = ^64)
  const int chnk = ((lane >> 4) ^ (lane & 7)) * 16;
  const int aB0 = (wr * 16 + (lane & 15)) * 128 + chnk;
  const int aB1 = aB0 ^ 64;
  const int bB0 = (wcn * 16 + (lane & 15)) * 128 + chnk;
  const int bB1 = bB0 ^ 64;

  f32x4 acc[8][4];
#pragma unroll
  for (int m = 0; m < 8; m++)
#pragma unroll
    for (int n = 0; n < 4; n++) acc[m][n] = (f32x4){0.f, 0.f, 0.f, 0.f};

#define STG_A(b, h, kt) { \
    gl_lds(srcA[0][h] + (kt) * 64, &Al[b][(h) * 8192 + (wid * 2 + 0) * 512]); \
    gl_lds(srcA[1][h] + (kt) * 64, &Al[b][(h) * 8192 + (wid * 2 + 1) * 512]); }
#define STG_B(b, h, kt) { \
    gl_lds(srcB[0] + (h) * 131072 + (kt) * 64, &Bl[b][(h) * 8192 + (wid * 2 + 0) * 512]); \
    gl_lds(srcB[1] + (h) * 131072 + (kt) * 64, &Bl[b][(h) * 8192 + (wid * 2 + 1) * 512]); }

  // prologue: FIFO order matching steady schedule
  STG_A(0, 0, 0); STG_B(0, 0, 0); STG_B(0, 1, 0); STG_A(0, 1, 0);
  STG_A(1, 0, 1); STG_B(1, 0, 1);
  asm volatile("s_waitcnt vmcnt(6)" ::: "memory");  // A0,B0,B1 of tile 0 landed
  __builtin_amdgcn_s_barrier();

#define KTBODY(KT, BUF) { \
    const int kA = ((KT) + 1 < 16) ? (KT) + 1 : 15; \
    const int kB = ((KT) + 2 < 16) ? (KT) + 2 : 15; \
    const char* pA = (const char*)(&Al[BUF][0]); \
    const char* pB = (const char*)(&Bl[BUF][0]); \
    short8 a[4], b0[4], b1[4]; \
    /* ---- q0: reads A(m0-3,ks0)+B(all n,ks0); stage B1(kt+1) ---- */ \
    _Pragma("unroll") for (int m = 0; m < 4; m++) a[m] = *(const short8*)(pA + aB0 + m * 4096); \
    _Pragma("unroll") for (int n = 0; n < 4; n++) b0[n] = *(const short8*)(pB + bB0 + (n & 1) * 8192 + (n >> 1) * 16384); \
    STG_B(BUF ^ 1, 1, kA); \
    __builtin_amdgcn_s_barrier(); \
    asm volatile("s_waitcnt lgkmcnt(0)" ::: "memory"); \
    __builtin_amdgcn_s_setprio(1); \
    _Pragma("unroll") for (int m = 0; m < 4; m++) \
      _Pragma("unroll") for (int n = 0; n < 4; n++) \
        acc[m][n] = __builtin_amdgcn_mfma_f32_16x16x32_bf16(a[m], b0[n], acc[m][n], 0, 0, 0); \
    __builtin_amdgcn_s_setprio(0); \
    __builtin_amdgcn_s_barrier(); \
    /* ---- q1: reads A(m0-3,ks1)+B(all n,ks1); stage A1(kt+1) ---- */ \
    _Pragma("unroll") for (int m = 0; m < 4; m++) a[m] = *(const short8*)(pA + aB1 + m * 4096); \
    _Pragma("unroll") for (int n = 0; n < 4; n++) b1[n] = *(const short8*)(pB + bB1 + (n & 1) * 8192 + (n >> 1) * 16384); \
    STG_A(BUF ^ 1, 1, kA); \
    __builtin_amdgcn_s_barrier(); \
    asm volatile("s_waitcnt lgkmcnt(0)" ::: "memory"); \
    __builtin_amdgcn_s_setprio(1); \
    _Pragma("unroll") for (int m = 0; m < 4; m++) \
      _Pragma("unroll") for (int n = 0; n < 4; n++) \
        acc[m][n] = __builtin_amdgcn_mfma_f32_16x16x32_bf16(a[m], b1[n], acc[m][n], 0, 0, 0); \
    __builtin_amdgcn_s_setprio(0); \
    asm volatile("s_waitcnt vmcnt(8)" ::: "memory"); \
    __builtin_amdgcn_s_barrier(); \
    /* ---- q2: reads A(m4-7,ks0); stage A0(kt+2); B held in regs ---- */ \
    _Pragma("unroll") for (int m = 0; m < 4; m++) a[m] = *(const short8*)(pA + aB0 + 16384 + m * 4096); \
    STG_A(BUF, 0, kB); \
    __builtin_amdgcn_s_barrier(); \
    asm volatile("s_waitcnt lgkmcnt(0)" ::: "memory"); \
    __builtin_amdgcn_s_setprio(1); \
    _Pragma("unroll") for (int m = 0; m < 4; m++) \
      _Pragma("unroll") for (int n = 0; n < 4; n++) \
        acc[m + 4][n] = __builtin_amdgcn_mfma_f32_16x16x32_bf16(a[m], b0[n], acc[m + 4][n], 0, 0, 0); \
    __builtin_amdgcn_s_setprio(0); \
    __builtin_amdgcn_s_barrier(); \
    /* ---- q3: reads A(m4-7,ks1); stage B0(kt+2) ---- */ \
    _Pragma("unroll") for (int m = 0; m < 4; m++) a[m] = *(const short8*)(pA + aB1 + 16384 + m * 4096); \
    STG_B(BUF, 0, kB); \
    __builtin_amdgcn_s_barrier(); \
    asm volatile("s_waitcnt lgkmcnt(0)" ::: "memory"); \
    __builtin_amdgcn_s_setprio(1); \
    _Pragma("unroll") for (int m = 0; m < 4; m++) \
      _Pragma("unroll") for (int n = 0; n < 4; n++) \
        acc[m + 4][n] = __builtin_amdgcn_mfma_f32_16x16x32_bf16(a[m], b1[n], acc[m + 4][n], 0, 0, 0); \
    __builtin_amdgcn_s_setprio(0); \
    asm volatile("s_waitcnt vmcnt(6)" ::: "memory"); \
    __builtin_amdgcn_s_barrier(); \
  }

  for (int kt2 = 0; kt2 < 16; kt2 += 2) {
    KTBODY(kt2, 0);
    KTBODY(kt2 + 1, 1);
  }
  asm volatile("s_waitcnt vmcnt(0)" ::: "memory");  // drain before exit

  // ---- epilogue (R6-verified mapping) ----
  if (FFN1) {
#pragma unroll
    for (int m = 0; m < 8; m++)
#pragma unroll
      for (int n = 0; n < 2; n++) {
        f32x4 v1 = acc[m][n], v3 = acc[m][n + 2];
        int col = nt * 128 + n * 64 + wcn * 16 + (lane & 15);
#pragma unroll
        for (int i = 0; i < 4; i++) {
          int row = m0 + (m >> 2) * 128 + (m & 3) * 32 + wr * 16 + ((lane >> 4) * 4) + i;
          if (row < cnt_e) {
            float a1v = v1[i];
            float hv = (a1v / (1.f + __expf(-a1v))) * v3[i];
            outp[(size_t)(bse + row) * DE + col] = (short)f2bf(hv);
          }
        }
      }
  } else {
#pragma unroll
    for (int m = 0; m < 8; m++)
#pragma unroll
      for (int n = 0; n < 4; n++) {
        f32x4 v = acc[m][n];
        int col = nt * 256 + (n >> 1) * 128 + (n & 1) * 64 + wcn * 16 + (lane & 15);
#pragma unroll
        for (int i = 0; i < 4; i++) {
          int row = m0 + (m >> 2) * 128 + (m & 3) * 32 + wr * 16 + ((lane >> 4) * 4) + i;
          if (row < cnt_e)
            outp[(size_t)(bse + row) * DM + col] = (short)f2bf(v[i]);
        }
      }
  }
}

// ---------------- combine: out[t] = w0*y[s0] + w1*y[s1] ----------------
__global__ __launch_bounds__(256) void k_combine(const short* __restrict__ y,
                                                 const int* __restrict__ slot_of_tok,
                                                 const float* __restrict__ wgt,
                                                 float* __restrict__ out) {
  int t = blockIdx.x;
  int s0 = slot_of_tok[2 * t], s1 = slot_of_tok[2 * t + 1];
  float w0 = wgt[2 * t], w1 = wgt[2 * t + 1];
  int c = threadIdx.x * 4;
  short4v a = *(const short4v*)(y + (size_t)s0 * DM + c);
  short4v b = *(const short4v*)(y + (size_t)s1 * DM + c);
  f32x4 o;
#pragma unroll
  for (int j = 0; j < 4; j++)
    o[j] = w0 * bf2f((unsigned short)a[j]) + w1 * bf2f((unsigned short)b[j]);
  *(f32x4*)(out + (size_t)t * DM + c) = o;
}

extern "C" void kernel_launch(void* const* d_in, const int* in_sizes, int n_in,
                              void* d_out, int out_size, void* d_ws, size_t ws_size,
                              hipStream_t stream) {
  const float* x  = (const float*)d_in[0];
  const float* Wr = (const float*)d_in[1];
  const float* W1 = (const float*)d_in[2];
  const float* W2 = (const float*)d_in[3];
  const float* W3 = (const float*)d_in[4];
  float* out = (float*)d_out;
  char* ws = (char*)d_ws;

  short* xb   = (short*)(ws);                   // 16 MB
  short* wcat = (short*)(ws + 16777216);        // 32 MB (8 x 2048 x 1024 bf16)
  short* w2t  = (short*)(ws + 50331648);        // 16 MB
  short* h    = (short*)(ws + 67108864);        // 32 MB
  short* y    = (short*)(ws + 100663296);       // 32 MB
  char* meta = ws + 134217728;
  int* cnt          = (int*)(meta);
  int* off          = (int*)(meta + 256);
  int* esel         = (int*)(meta + 512);
  int* rank         = (int*)(meta + 512 + 65536);
  int* tok_of_slot  = (int*)(meta + 512 + 2 * 65536);
  int* slot_of_tok  = (int*)(meta + 512 + 3 * 65536);
  float* wgt        = (float*)(meta + 512 + 4 * 65536);

  hipMemsetAsync(cnt, 0, 32, stream);
  k_transw<<<dim3(16, 16, 24), 256, 0, stream>>>(W1, W2, W3, wcat, w2t);
  k_router<<<2048, 256, 0, stream>>>(x, Wr, xb, esel, wgt);
  k_rank<<<32, 256, 0, stream>>>(esel, cnt, rank);
  k_offsets<<<1, 64, 0, stream>>>(cnt, off);
  k_scatter<<<32, 256, 0, stream>>>(off, esel, rank, tok_of_slot, slot_of_tok);
  k_ffn<1><<<dim3(8, 8, 32), 512, 0, stream>>>(xb, wcat, cnt, off, tok_of_slot, h);
  k_ffn<0><<<dim3(4, 8, 32), 512, 0, stream>>>(h, w2t, cnt, off, tok_of_slot, y);
  k_combine<<<8192, 256, 0, stream>>>(y, slot_of_tok, wgt, out);
}

// Round 10
// 246.207 us; speedup vs baseline: 1.1039x; 1.1039x over previous
//
#include <hip/hip_runtime.h>
#include <hip/hip_bf16.h>

typedef __attribute__((ext_vector_type(8))) short short8;
typedef __attribute__((ext_vector_type(4))) short short4v;
typedef __attribute__((ext_vector_type(4))) unsigned short ushort4v;
typedef __attribute__((ext_vector_type(4))) float f32x4;

#define NTOK 8192
#define DM 1024
#define DE 1024
#define NE 8

__device__ __forceinline__ float bf2f(unsigned short u) {
  union { unsigned int i; float f; } v; v.i = ((unsigned int)u) << 16; return v.f;
}
__device__ __forceinline__ unsigned short f2bf(float f) {
  union { float f; unsigned int i; } v; v.f = f;
  unsigned int lsb = (v.i >> 16) & 1;
  v.i += 0x7fffu + lsb;  // RNE; inputs finite
  return (unsigned short)(v.i >> 16);
}
__device__ __forceinline__ void gl_lds(const short* g, short* l) {
  __builtin_amdgcn_global_load_lds((const __attribute__((address_space(1))) void*)g,
                                   (__attribute__((address_space(3))) void*)l, 16, 0, 0);
}

// ------- W fp32 [K][N] -> bf16 transposed; W1/W3 interleaved into wcat -------
// wcat[e]: 2048 rows in 128-row groups: group g rows [g*128, g*128+64) = W1^T
//          cols g*64+[0,64); rows +64 = W3^T same cols.
// w2t[e]: plain W2^T [1024][1024]
__global__ __launch_bounds__(256) void k_transw(const float* __restrict__ W1,
                                                const float* __restrict__ W2,
                                                const float* __restrict__ W3,
                                                short* __restrict__ wcat,
                                                short* __restrict__ w2t) {
  __shared__ float t[64][65];
  int mid = blockIdx.z;
  const float* src;
  if (mid < 8)       src = W1 + (size_t)mid * (DM * DE);
  else if (mid < 16) src = W3 + (size_t)(mid - 8) * (DM * DE);
  else               src = W2 + (size_t)(mid - 16) * (DE * DM);
  int tid = threadIdx.x;
  int tr = tid >> 4, tc = tid & 15;
  int kbase = blockIdx.y * 64, nbase = blockIdx.x * 64;
#pragma unroll
  for (int j = 0; j < 4; j++) {
    int kr = tr + j * 16;
    f32x4 v = *(const f32x4*)(src + (size_t)(kbase + kr) * 1024 + nbase + tc * 4);
    t[kr][tc * 4 + 0] = v[0]; t[kr][tc * 4 + 1] = v[1];
    t[kr][tc * 4 + 2] = v[2]; t[kr][tc * 4 + 3] = v[3];
  }
  __syncthreads();
#pragma unroll
  for (int j = 0; j < 4; j++) {
    int n = tr + j * 16;          // source column (0..1023 within this matrix)
    int ng = nbase + n;
    short4v o;
    o[0] = (short)f2bf(t[tc * 4 + 0][n]);
    o[1] = (short)f2bf(t[tc * 4 + 1][n]);
    o[2] = (short)f2bf(t[tc * 4 + 2][n]);
    o[3] = (short)f2bf(t[tc * 4 + 3][n]);
    size_t dsto;
    if (mid < 16) {
      int e = mid & 7, p = mid >> 3;
      int row_out = ((ng >> 6) * 128) + p * 64 + (ng & 63);
      dsto = (size_t)e * (2048 * 1024) + (size_t)row_out * 1024 + kbase + tc * 4;
      *(short4v*)(wcat + dsto) = o;
    } else {
      int e = mid - 16;
      dsto = (size_t)e * (1024 * 1024) + (size_t)ng * 1024 + kbase + tc * 4;
      *(short4v*)(w2t + dsto) = o;
    }
  }
}

// ------- router: fp32 logits, softmax-top2, fused x->bf16 conversion -------
__global__ __launch_bounds__(256) void k_router(const float* __restrict__ x,
                                                const float* __restrict__ Wr,
                                                short* __restrict__ xb,
                                                int* __restrict__ esel,
                                                float* __restrict__ wgt) {
  int wid = threadIdx.x >> 6, lane = threadIdx.x & 63;
  int t = blockIdx.x * 4 + wid;
  const float* xr = x + (size_t)t * DM;
  float acc[8];
#pragma unroll
  for (int e = 0; e < 8; e++) acc[e] = 0.f;
#pragma unroll
  for (int i = 0; i < 4; i++) {
    int kb = (i * 64 + lane) * 4;
    f32x4 v = *(const f32x4*)(xr + kb);
    ushort4v ob;
#pragma unroll
    for (int j = 0; j < 4; j++) {
      f32x4 w0 = *(const f32x4*)(Wr + (size_t)(kb + j) * 8);
      f32x4 w1 = *(const f32x4*)(Wr + (size_t)(kb + j) * 8 + 4);
      float xv = v[j];
      ob[j] = f2bf(xv);
      acc[0] += xv * w0[0]; acc[1] += xv * w0[1];
      acc[2] += xv * w0[2]; acc[3] += xv * w0[3];
      acc[4] += xv * w1[0]; acc[5] += xv * w1[1];
      acc[6] += xv * w1[2]; acc[7] += xv * w1[3];
    }
    *(ushort4v*)(xb + (size_t)t * DM + kb) = ob;
  }
#pragma unroll
  for (int off = 32; off; off >>= 1)
#pragma unroll
    for (int e = 0; e < 8; e++) acc[e] += __shfl_xor(acc[e], off);
  float m0 = -1e30f, m1 = -1e30f; int e0 = 0, e1 = 0;
#pragma unroll
  for (int e = 0; e < 8; e++) {
    float v = acc[e];
    if (v > m0) { m1 = m0; e1 = e0; m0 = v; e0 = e; }
    else if (v > m1) { m1 = v; e1 = e; }
  }
  float p = __expf(m1 - m0);
  if (lane == 0) {
    esel[2 * t] = e0; esel[2 * t + 1] = e1;
    wgt[2 * t] = 1.f / (1.f + p); wgt[2 * t + 1] = p / (1.f + p);
  }
}

// ---- ranks via wave ballots + per-block aggregated atomics ----
__global__ __launch_bounds__(256) void k_rank(const int* __restrict__ esel,
                                              int* __restrict__ cnt,
                                              int* __restrict__ rank) {
  __shared__ int wcnt[4][8];
  __shared__ int woff[4][8];
  int tid = threadIdx.x;
  int lane = tid & 63, wid = tid >> 6;
  int t = blockIdx.x * 256 + tid;
  int e0 = esel[2 * t], e1 = esel[2 * t + 1];
  unsigned long long lt = (lane == 0) ? 0ull : ((~0ull) >> (64 - lane));
  int r0 = 0, r1 = 0;
#pragma unroll
  for (int e = 0; e < 8; e++) {
    unsigned long long m0 = __ballot(e0 == e);
    unsigned long long m1 = __ballot(e1 == e);
    int c0 = __popcll(m0);
    if (e0 == e) r0 = __popcll(m0 & lt);
    if (e1 == e) r1 = c0 + __popcll(m1 & lt);
    if (lane == 0) wcnt[wid][e] = c0 + __popcll(m1);
  }
  __syncthreads();
  if (tid < 8) {
    int e = tid;
    int c0 = wcnt[0][e], c1 = wcnt[1][e], c2 = wcnt[2][e], c3 = wcnt[3][e];
    int base = atomicAdd(&cnt[e], c0 + c1 + c2 + c3);
    woff[0][e] = base;
    woff[1][e] = base + c0;
    woff[2][e] = base + c0 + c1;
    woff[3][e] = base + c0 + c1 + c2;
  }
  __syncthreads();
  rank[2 * t] = woff[wid][e0] + r0;
  rank[2 * t + 1] = woff[wid][e1] + r1;
}

__global__ void k_offsets(const int* __restrict__ cnt, int* __restrict__ off) {
  if (threadIdx.x == 0) {
    int s = 0;
    for (int e = 0; e < NE; e++) { off[e] = s; s += cnt[e]; }
  }
}

__global__ __launch_bounds__(256) void k_scatter(const int* __restrict__ off,
                                                 const int* __restrict__ esel,
                                                 const int* __restrict__ rank,
                                                 int* __restrict__ tok_of_slot,
                                                 int* __restrict__ slot_of_tok) {
  int t = blockIdx.x * 256 + threadIdx.x;
#pragma unroll
  for (int j = 0; j < 2; j++) {
    int e = esel[2 * t + j];
    int s = off[e] + rank[2 * t + j];
    tok_of_slot[s] = t;
    slot_of_tok[2 * t + j] = s;
  }
}

// == 128x128-tile BK=32 grouped GEMM, reg-level fragment double-buffer ==
// R1-R9 synthesis: pipes were running SERIALLY (ds_read->MFMA dependency +
// lockstep barriers). Fix: read tile t+1's fragments into a SECOND register
// set while tile t's MFMAs execute -> LDS pipe runs under matrix pipe.
// Geometry forced by reg budget: 4 waves (2Mx2N) of 64x64, acc[4][4]=64 +
// two frag sets 64 + addr ~40 ~= 168 <= 170 (launch_bounds(256,3): 3 blocks/CU,
// 3 waves/SIMD). LDS: 2-ring x (A 8KB + B 8KB) = 32 KB -> 3 blocks = 96 KB.
// Step t: stage(t+2)->slot t&1 (dead since t-1's barrier) || 8 ds_reads of
// frags(t+1) from slot (t+1)&1 || 16 MFMA(t) -> lgkmcnt(0) (reads done before
// next step overwrites their slot) -> vmcnt(0) (stage(t+2) landed; issued a
// full step earlier so latency is hidden; 3 independent blocks absorb the
// drain) -> single barrier. Unroll x2: reg-set parity == slot parity.
// FFN1=1: A = xb gathered via tok_of_slot, B = wcat (128-row group = 64 W1 +
//         64 W3 col pairs), epilogue silu(a1)*a3 -> h (64 cols/blk)
// FFN1=0: A = h (slot rows), B = w2t, epilogue -> y (128 cols/blk)
template<int FFN1>
__global__ __launch_bounds__(256, 3) void k_ffn(const short* __restrict__ Abase,
                                                const short* __restrict__ Bbase,
                                                const int* __restrict__ cnt,
                                                const int* __restrict__ off,
                                                const int* __restrict__ tok_of_slot,
                                                short* __restrict__ outp) {
  const int e = blockIdx.y;
  const int cnt_e = cnt[e];
  const int m0 = blockIdx.z * 128;
  if (m0 >= cnt_e) return;
  const int bse = off[e];
  const int nt = blockIdx.x;
  const short* Bt = Bbase + (size_t)e * ((FFN1 ? 2048 : 1024) * 1024) + (size_t)(nt * 128) * 1024;

  // k-tile: A 128x32 bf16 = 8 KB (4096 shorts), B 128x32 = 8 KB
  __shared__ __align__(128) short Al[2][4096];  // 16 KB
  __shared__ __align__(128) short Bl[2][4096];  // 16 KB (32 KB total)

  const int tid = threadIdx.x;
  const int lane = tid & 63, wid = tid >> 6;   // 4 waves
  const int wr = wid >> 1, wcn = wid & 1;      // 2M x 2N, wave tile 64x64

  // staging: chunk ch = tid + i*256; row r = ch>>2; src col-chunk
  // c = (ch&3) ^ ((r>>1)&3)  (inverse-swizzled source, linear LDS dest)
  const short* srcA[2]; const short* srcB[2];
#pragma unroll
  for (int i = 0; i < 2; i++) {
    int ch = tid + i * 256;
    int r = ch >> 2, c = (ch & 3) ^ ((r >> 1) & 3);
    int row = m0 + r; if (row >= cnt_e) row = cnt_e - 1;
    long ar = FFN1 ? (long)tok_of_slot[bse + row] : (long)(bse + row);
    srcA[i] = Abase + ar * 1024 + c * 8;
    srcB[i] = Bt + (size_t)r * 1024 + c * 8;
  }

  // fragment LDS byte offsets (proven 0-conflict read pattern)
  int aoff[4], boff[4];
#pragma unroll
  for (int m = 0; m < 4; m++) {
    int r = wr * 64 + m * 16 + (lane & 15);
    aoff[m] = (r * 4 + ((lane >> 4) ^ ((r >> 1) & 3))) * 16;
  }
#pragma unroll
  for (int n = 0; n < 4; n++) {
    int rb = FFN1 ? (wcn * 32 + (n & 1) * 16 + (n >> 1) * 64 + (lane & 15))
                  : (wcn * 64 + n * 16 + (lane & 15));
    boff[n] = (rb * 4 + ((lane >> 4) ^ ((rb >> 1) & 3))) * 16;
  }

  f32x4 acc[4][4];
#pragma unroll
  for (int m = 0; m < 4; m++)
#pragma unroll
    for (int n = 0; n < 4; n++) acc[m][n] = (f32x4){0.f, 0.f, 0.f, 0.f};

#define STG(P, kt) { gl_lds(srcA[0] + (kt) * 32, &Al[P][(tid + 0) * 8]); \
                     gl_lds(srcA[1] + (kt) * 32, &Al[P][(tid + 256) * 8]); \
                     gl_lds(srcB[0] + (kt) * 32, &Bl[P][(tid + 0) * 8]); \
                     gl_lds(srcB[1] + (kt) * 32, &Bl[P][(tid + 256) * 8]); }

  short8 a0[4], b0[4], a1[4], b1[4];

  // prologue: stage tiles 0,1; read frags(0) -> set0; fully drain
  STG(0, 0); STG(1, 1);
  asm volatile("s_waitcnt vmcnt(4)" ::: "memory");  // stage(0) landed
  __builtin_amdgcn_s_barrier();
  {
    const char* An = (const char*)Al[0];
    const char* Bn = (const char*)Bl[0];
#pragma unroll
    for (int m = 0; m < 4; m++) a0[m] = *(const short8*)(An + aoff[m]);
#pragma unroll
    for (int n = 0; n < 4; n++) b0[n] = *(const short8*)(Bn + boff[n]);
  }
  asm volatile("s_waitcnt lgkmcnt(0)" ::: "memory");
  asm volatile("s_waitcnt vmcnt(0)" ::: "memory");  // stage(1) landed too
  __builtin_amdgcn_s_barrier();

  // step T (parity P=T&1): stage(T+2)->slot P; read frags(T+1) from slot P^1
  // into next set; MFMA(T) from current set; lgkm+vm drain; barrier.
#define STEP(T, P, CA, CB, NA, NB) { \
    const int ktn = ((T) + 2 < 32) ? (T) + 2 : 31; \
    STG(P, ktn); \
    const char* An = (const char*)Al[(P) ^ 1]; \
    const char* Bn = (const char*)Bl[(P) ^ 1]; \
    _Pragma("unroll") for (int m = 0; m < 4; m++) NA[m] = *(const short8*)(An + aoff[m]); \
    _Pragma("unroll") for (int n = 0; n < 4; n++) NB[n] = *(const short8*)(Bn + boff[n]); \
    __builtin_amdgcn_s_setprio(1); \
    _Pragma("unroll") for (int m = 0; m < 4; m++) \
      _Pragma("unroll") for (int n = 0; n < 4; n++) \
        acc[m][n] = __builtin_amdgcn_mfma_f32_16x16x32_bf16(CA[m], CB[n], acc[m][n], 0, 0, 0); \
    __builtin_amdgcn_s_setprio(0); \
    asm volatile("s_waitcnt lgkmcnt(0)" ::: "memory"); \
    asm volatile("s_waitcnt vmcnt(0)" ::: "memory"); \
    __builtin_amdgcn_s_barrier(); }

  for (int t2 = 0; t2 < 16; ++t2) {
    const int t = t2 * 2;
    STEP(t,     0, a0, b0, a1, b1);
    STEP(t + 1, 1, a1, b1, a0, b0);
  }

  // ---- epilogue ----
  if (FFN1) {
#pragma unroll
    for (int m = 0; m < 4; m++)
#pragma unroll
      for (int cc = 0; cc < 2; cc++) {
        f32x4 v1 = acc[m][cc], v3 = acc[m][cc + 2];
        int col = nt * 64 + wcn * 32 + cc * 16 + (lane & 15);
#pragma unroll
        for (int i = 0; i < 4; i++) {
          int row = m0 + wr * 64 + m * 16 + ((lane >> 4) * 4) + i;
          if (row < cnt_e) {
            float a1v = v1[i];
            float hv = (a1v / (1.f + __expf(-a1v))) * v3[i];
            outp[(size_t)(bse + row) * DE + col] = (short)f2bf(hv);
          }
        }
      }
  } else {
#pragma unroll
    for (int m = 0; m < 4; m++)
#pragma unroll
      for (int n = 0; n < 4; n++) {
        f32x4 v = acc[m][n];
        int col = nt * 128 + wcn * 64 + n * 16 + (lane & 15);
#pragma unroll
        for (int i = 0; i < 4; i++) {
          int row = m0 + wr * 64 + m * 16 + ((lane >> 4) * 4) + i;
          if (row < cnt_e)
            outp[(size_t)(bse + row) * DM + col] = (short)f2bf(v[i]);
        }
      }
  }
}

// ---------------- combine: out[t] = w0*y[s0] + w1*y[s1] ----------------
__global__ __launch_bounds__(256) void k_combine(const short* __restrict__ y,
                                                 const int* __restrict__ slot_of_tok,
                                                 const float* __restrict__ wgt,
                                                 float* __restrict__ out) {
  int t = blockIdx.x;
  int s0 = slot_of_tok[2 * t], s1 = slot_of_tok[2 * t + 1];
  float w0 = wgt[2 * t], w1 = wgt[2 * t + 1];
  int c = threadIdx.x * 4;
  short4v a = *(const short4v*)(y + (size_t)s0 * DM + c);
  short4v b = *(const short4v*)(y + (size_t)s1 * DM + c);
  f32x4 o;
#pragma unroll
  for (int j = 0; j < 4; j++)
    o[j] = w0 * bf2f((unsigned short)a[j]) + w1 * bf2f((unsigned short)b[j]);
  *(f32x4*)(out + (size_t)t * DM + c) = o;
}

extern "C" void kernel_launch(void* const* d_in, const int* in_sizes, int n_in,
                              void* d_out, int out_size, void* d_ws, size_t ws_size,
                              hipStream_t stream) {
  const float* x  = (const float*)d_in[0];
  const float* Wr = (const float*)d_in[1];
  const float* W1 = (const float*)d_in[2];
  const float* W2 = (const float*)d_in[3];
  const float* W3 = (const float*)d_in[4];
  float* out = (float*)d_out;
  char* ws = (char*)d_ws;

  short* xb   = (short*)(ws);                   // 16 MB
  short* wcat = (short*)(ws + 16777216);        // 32 MB (8 x 2048 x 1024 bf16)
  short* w2t  = (short*)(ws + 50331648);        // 16 MB
  short* h    = (short*)(ws + 67108864);        // 32 MB
  short* y    = (short*)(ws + 100663296);       // 32 MB
  char* meta = ws + 134217728;
  int* cnt          = (int*)(meta);
  int* off          = (int*)(meta + 256);
  int* esel         = (int*)(meta + 512);
  int* rank         = (int*)(meta + 512 + 65536);
  int* tok_of_slot  = (int*)(meta + 512 + 2 * 65536);
  int* slot_of_tok  = (int*)(meta + 512 + 3 * 65536);
  float* wgt        = (float*)(meta + 512 + 4 * 65536);

  hipMemsetAsync(cnt, 0, 32, stream);
  k_transw<<<dim3(16, 16, 24), 256, 0, stream>>>(W1, W2, W3, wcat, w2t);
  k_router<<<2048, 256, 0, stream>>>(x, Wr, xb, esel, wgt);
  k_rank<<<32, 256, 0, stream>>>(esel, cnt, rank);
  k_offsets<<<1, 64, 0, stream>>>(cnt, off);
  k_scatter<<<32, 256, 0, stream>>>(off, esel, rank, tok_of_slot, slot_of_tok);
  k_ffn<1><<<dim3(16, 8, 64), 256, 0, stream>>>(xb, wcat, cnt, off, tok_of_slot, h);
  k_ffn<0><<<dim3(8, 8, 64), 256, 0, stream>>>(h, w2t, cnt, off, tok_of_slot, y);
  k_combine<<<8192, 256, 0, stream>>>(y, slot_of_tok, wgt, out);
}

// Round 11
// 236.471 us; speedup vs baseline: 1.1493x; 1.0412x over previous
//
#include <hip/hip_runtime.h>
#include <hip/hip_bf16.h>

typedef __attribute__((ext_vector_type(8))) short short8;
typedef __attribute__((ext_vector_type(4))) short short4v;
typedef __attribute__((ext_vector_type(4))) unsigned short ushort4v;
typedef __attribute__((ext_vector_type(4))) float f32x4;

#define NTOK 8192
#define DM 1024
#define DE 1024
#define NE 8

__device__ __forceinline__ float bf2f(unsigned short u) {
  union { unsigned int i; float f; } v; v.i = ((unsigned int)u) << 16; return v.f;
}
__device__ __forceinline__ unsigned short f2bf(float f) {
  union { float f; unsigned int i; } v; v.f = f;
  unsigned int lsb = (v.i >> 16) & 1;
  v.i += 0x7fffu + lsb;  // RNE; inputs finite
  return (unsigned short)(v.i >> 16);
}
__device__ __forceinline__ void gl_lds(const short* g, short* l) {
  __builtin_amdgcn_global_load_lds((const __attribute__((address_space(1))) void*)g,
                                   (__attribute__((address_space(3))) void*)l, 16, 0, 0);
}

// ------- W fp32 [K][N] -> bf16 transposed; W1/W3 interleaved into wcat -------
// wcat[e]: 2048 rows in 128-row groups: group g rows [g*128, g*128+64) = W1^T
//          cols g*64+[0,64); rows +64 = W3^T same cols.
// w2t[e]: plain W2^T [1024][1024]
__global__ __launch_bounds__(256) void k_transw(const float* __restrict__ W1,
                                                const float* __restrict__ W2,
                                                const float* __restrict__ W3,
                                                short* __restrict__ wcat,
                                                short* __restrict__ w2t) {
  __shared__ float t[64][65];
  int mid = blockIdx.z;
  const float* src;
  if (mid < 8)       src = W1 + (size_t)mid * (DM * DE);
  else if (mid < 16) src = W3 + (size_t)(mid - 8) * (DM * DE);
  else               src = W2 + (size_t)(mid - 16) * (DE * DM);
  int tid = threadIdx.x;
  int tr = tid >> 4, tc = tid & 15;
  int kbase = blockIdx.y * 64, nbase = blockIdx.x * 64;
#pragma unroll
  for (int j = 0; j < 4; j++) {
    int kr = tr + j * 16;
    f32x4 v = *(const f32x4*)(src + (size_t)(kbase + kr) * 1024 + nbase + tc * 4);
    t[kr][tc * 4 + 0] = v[0]; t[kr][tc * 4 + 1] = v[1];
    t[kr][tc * 4 + 2] = v[2]; t[kr][tc * 4 + 3] = v[3];
  }
  __syncthreads();
#pragma unroll
  for (int j = 0; j < 4; j++) {
    int n = tr + j * 16;          // source column (0..1023 within this matrix)
    int ng = nbase + n;
    short4v o;
    o[0] = (short)f2bf(t[tc * 4 + 0][n]);
    o[1] = (short)f2bf(t[tc * 4 + 1][n]);
    o[2] = (short)f2bf(t[tc * 4 + 2][n]);
    o[3] = (short)f2bf(t[tc * 4 + 3][n]);
    size_t dsto;
    if (mid < 16) {
      int e = mid & 7, p = mid >> 3;
      int row_out = ((ng >> 6) * 128) + p * 64 + (ng & 63);
      dsto = (size_t)e * (2048 * 1024) + (size_t)row_out * 1024 + kbase + tc * 4;
      *(short4v*)(wcat + dsto) = o;
    } else {
      int e = mid - 16;
      dsto = (size_t)e * (1024 * 1024) + (size_t)ng * 1024 + kbase + tc * 4;
      *(short4v*)(w2t + dsto) = o;
    }
  }
}

// ------- router: fp32 logits, softmax-top2, fused x->bf16 conversion -------
__global__ __launch_bounds__(256) void k_router(const float* __restrict__ x,
                                                const float* __restrict__ Wr,
                                                short* __restrict__ xb,
                                                int* __restrict__ esel,
                                                float* __restrict__ wgt) {
  int wid = threadIdx.x >> 6, lane = threadIdx.x & 63;
  int t = blockIdx.x * 4 + wid;
  const float* xr = x + (size_t)t * DM;
  float acc[8];
#pragma unroll
  for (int e = 0; e < 8; e++) acc[e] = 0.f;
#pragma unroll
  for (int i = 0; i < 4; i++) {
    int kb = (i * 64 + lane) * 4;
    f32x4 v = *(const f32x4*)(xr + kb);
    ushort4v ob;
#pragma unroll
    for (int j = 0; j < 4; j++) {
      f32x4 w0 = *(const f32x4*)(Wr + (size_t)(kb + j) * 8);
      f32x4 w1 = *(const f32x4*)(Wr + (size_t)(kb + j) * 8 + 4);
      float xv = v[j];
      ob[j] = f2bf(xv);
      acc[0] += xv * w0[0]; acc[1] += xv * w0[1];
      acc[2] += xv * w0[2]; acc[3] += xv * w0[3];
      acc[4] += xv * w1[0]; acc[5] += xv * w1[1];
      acc[6] += xv * w1[2]; acc[7] += xv * w1[3];
    }
    *(ushort4v*)(xb + (size_t)t * DM + kb) = ob;
  }
#pragma unroll
  for (int off = 32; off; off >>= 1)
#pragma unroll
    for (int e = 0; e < 8; e++) acc[e] += __shfl_xor(acc[e], off);
  float m0 = -1e30f, m1 = -1e30f; int e0 = 0, e1 = 0;
#pragma unroll
  for (int e = 0; e < 8; e++) {
    float v = acc[e];
    if (v > m0) { m1 = m0; e1 = e0; m0 = v; e0 = e; }
    else if (v > m1) { m1 = v; e1 = e; }
  }
  float p = __expf(m1 - m0);
  if (lane == 0) {
    esel[2 * t] = e0; esel[2 * t + 1] = e1;
    wgt[2 * t] = 1.f / (1.f + p); wgt[2 * t + 1] = p / (1.f + p);
  }
}

// ---- ranks via wave ballots + per-block aggregated atomics ----
__global__ __launch_bounds__(256) void k_rank(const int* __restrict__ esel,
                                              int* __restrict__ cnt,
                                              int* __restrict__ rank) {
  __shared__ int wcnt[4][8];
  __shared__ int woff[4][8];
  int tid = threadIdx.x;
  int lane = tid & 63, wid = tid >> 6;
  int t = blockIdx.x * 256 + tid;
  int e0 = esel[2 * t], e1 = esel[2 * t + 1];
  unsigned long long lt = (lane == 0) ? 0ull : ((~0ull) >> (64 - lane));
  int r0 = 0, r1 = 0;
#pragma unroll
  for (int e = 0; e < 8; e++) {
    unsigned long long m0 = __ballot(e0 == e);
    unsigned long long m1 = __ballot(e1 == e);
    int c0 = __popcll(m0);
    if (e0 == e) r0 = __popcll(m0 & lt);
    if (e1 == e) r1 = c0 + __popcll(m1 & lt);
    if (lane == 0) wcnt[wid][e] = c0 + __popcll(m1);
  }
  __syncthreads();
  if (tid < 8) {
    int e = tid;
    int c0 = wcnt[0][e], c1 = wcnt[1][e], c2 = wcnt[2][e], c3 = wcnt[3][e];
    int base = atomicAdd(&cnt[e], c0 + c1 + c2 + c3);
    woff[0][e] = base;
    woff[1][e] = base + c0;
    woff[2][e] = base + c0 + c1;
    woff[3][e] = base + c0 + c1 + c2;
  }
  __syncthreads();
  rank[2 * t] = woff[wid][e0] + r0;
  rank[2 * t + 1] = woff[wid][e1] + r1;
}

// ---- scatter: prefix computed inline from cnt (k_offsets launch removed) ----
__global__ __launch_bounds__(256) void k_scatter(const int* __restrict__ cnt,
                                                 const int* __restrict__ esel,
                                                 const int* __restrict__ rank,
                                                 int* __restrict__ tok_of_slot,
                                                 int* __restrict__ slot_of_tok) {
  int t = blockIdx.x * 256 + threadIdx.x;
#pragma unroll
  for (int j = 0; j < 2; j++) {
    int e = esel[2 * t + j];
    int base = 0;
#pragma unroll
    for (int i = 0; i < NE; i++) base += (i < e) ? cnt[i] : 0;
    int s = base + rank[2 * t + j];
    tok_of_slot[s] = t;
    slot_of_tok[2 * t + j] = s;
  }
}

// ============ 256x128-tile BK=32 grouped GEMM, 3-ring counted-vmcnt ============
// R3 (best measured: 237.4 us total): R1 inner loop (0-conflict 16x16x32
// fragment reads, 2 barriers/tile, 2 blocks/CU) + expert-per-XCD remap:
//   flat grid; lid -> bijective chunked swizzle: XCD c = lid&7 processes
//   expert c only, panels (ntile) sequential, mtile fastest. The 8 active
//   m-tile blocks sharing a B-panel become consecutive on one XCD ->
//   panel fetched once from HBM, 7x L2 hits; A-gather rows stay XCD-local
//   with 16x reuse; FFN2 reads h written by the same XCD. (FETCH 82 MB,
//   the lowest of all 11 mappings tried.)
// bse (expert slot base) computed inline from cnt (k_offsets deleted).
// FFN1=1: A = xb gathered via tok_of_slot, B = wcat (128-row group = 64 W1 +
//         64 W3 col pairs), epilogue silu(a1)*a3 -> h (64 cols/blk)
// FFN1=0: A = h (slot rows), B = w2t, epilogue -> y (128 cols/blk)
template<int FFN1>
__global__ __launch_bounds__(512, 4) void k_ffn(const short* __restrict__ Abase,
                                                const short* __restrict__ Bbase,
                                                const int* __restrict__ cnt,
                                                const int* __restrict__ tok_of_slot,
                                                short* __restrict__ outp) {
  const int NT = FFN1 ? 16 : 8;        // ntiles per expert
  const int lid = blockIdx.x;          // flat grid: 32*8*NT blocks
  const int q = 32 * NT;               // blocks per XCD (total/8)
  const int swz = (lid & 7) * q + (lid >> 3);
  const int mt = swz & 31;
  const int pnl = swz >> 5;
  const int e = pnl / NT;              // == lid&7 : one expert per XCD
  const int nt = pnl % NT;

  const int cnt_e = cnt[e];
  const int m0 = mt * 256;
  if (m0 >= cnt_e) return;
  int bse = 0;
#pragma unroll
  for (int i = 0; i < NE; i++) bse += (i < e) ? cnt[i] : 0;
  const int n0 = nt * 128;
  const short* Bt = Bbase + (size_t)e * ((FFN1 ? 2048 : 1024) * 1024) + (size_t)n0 * 1024;

  // one k-tile: A 256x32 bf16 = 16 KB (8192 shorts), B 128x32 = 8 KB (4096)
  __shared__ __align__(128) short Al[3][8192];  // 48 KB
  __shared__ __align__(128) short Bl[3][4096];  // 24 KB  (72 KB total/block)

  const int tid = threadIdx.x;
  const int lane = tid & 63, wid = tid >> 6;
  const int wr = wid >> 1, wcn = wid & 1;

  // staging sources: chunk ch; row r = ch>>2; src col-chunk
  // c = (ch&3) ^ ((r>>1)&3)  (inverse-swizzled source, linear LDS dest)
  const short* srcA0; const short* srcA1; const short* srcB0;
  {
    int r0 = tid >> 2, c0 = (tid & 3) ^ ((r0 >> 1) & 3);
    int row0 = m0 + r0; if (row0 >= cnt_e) row0 = cnt_e - 1;
    long ar0 = FFN1 ? (long)tok_of_slot[bse + row0] : (long)(bse + row0);
    srcA0 = Abase + ar0 * 1024 + c0 * 8;
    int ch1 = tid + 512;
    int r1 = ch1 >> 2, c1 = (ch1 & 3) ^ ((r1 >> 1) & 3);
    int row1 = m0 + r1; if (row1 >= cnt_e) row1 = cnt_e - 1;
    long ar1 = FFN1 ? (long)tok_of_slot[bse + row1] : (long)(bse + row1);
    srcA1 = Abase + ar1 * 1024 + c1 * 8;
    srcB0 = Bt + (size_t)r0 * 1024 + c0 * 8;   // r0 < 128 for tid < 512
  }
  const int lA0 = wid * 512, lA1 = wid * 512 + 4096, lB0 = wid * 512;

  // fragment LDS byte offsets (swizzled read side) — proven 0-conflict pattern
  int aoff[4], boff[4];
#pragma unroll
  for (int m = 0; m < 4; m++) {
    int r = wr * 64 + m * 16 + (lane & 15);
    aoff[m] = (r * 4 + ((lane >> 4) ^ ((r >> 1) & 3))) * 16;
  }
#pragma unroll
  for (int n = 0; n < 4; n++) {
    int rb = FFN1 ? (wcn * 32 + (n & 1) * 16 + (n >> 1) * 64 + (lane & 15))
                  : (wcn * 64 + n * 16 + (lane & 15));
    boff[n] = (rb * 4 + ((lane >> 4) ^ ((rb >> 1) & 3))) * 16;
  }

  f32x4 acc[4][4];
#pragma unroll
  for (int m = 0; m < 4; m++)
#pragma unroll
    for (int n = 0; n < 4; n++) acc[m][n] = (f32x4){0.f, 0.f, 0.f, 0.f};

#define STG_A(b, kt) { gl_lds(srcA0 + (kt) * 32, &Al[b][lA0]); \
                       gl_lds(srcA1 + (kt) * 32, &Al[b][lA1]); }
#define STG_B(b, kt) { gl_lds(srcB0 + (kt) * 32, &Bl[b][lB0]); }

  // prologue: tiles 0,1 issued (3 loads each); wait tile 0 (tile 1 in flight)
  STG_A(0, 0); STG_B(0, 0);
  STG_A(1, 1); STG_B(1, 1);
  asm volatile("s_waitcnt vmcnt(3)" ::: "memory");
  __builtin_amdgcn_s_barrier();

  int cur = 0, nxt = 2;
  for (int t = 0; t < 32; ++t) {
    int ktn = (t + 2 < 32) ? (t + 2) : 31;  // clamped dup-stage: same bytes, benign
    const char* Ab = (const char*)Al[cur];
    const char* Bb = (const char*)Bl[cur];
    short8 a[4], b[4];
#pragma unroll
    for (int m = 0; m < 4; m++) a[m] = *(const short8*)(Ab + aoff[m]);
#pragma unroll
    for (int n = 0; n < 4; n++) b[n] = *(const short8*)(Bb + boff[n]);
    STG_A(nxt, ktn); STG_B(nxt, ktn);
    __builtin_amdgcn_s_barrier();
    __builtin_amdgcn_s_setprio(1);
#pragma unroll
    for (int m = 0; m < 4; m++)
#pragma unroll
      for (int n = 0; n < 4; n++)
        acc[m][n] = __builtin_amdgcn_mfma_f32_16x16x32_bf16(a[m], b[n], acc[m][n], 0, 0, 0);
    __builtin_amdgcn_s_setprio(0);
    asm volatile("s_waitcnt vmcnt(3)" ::: "memory");  // tile t+1 arrived; t+2 in flight
    __builtin_amdgcn_s_barrier();
    cur = (cur == 2) ? 0 : cur + 1;
    nxt = (nxt == 2) ? 0 : nxt + 1;
  }
  asm volatile("s_waitcnt vmcnt(0)" ::: "memory");  // drain before LDS dealloc

  // ---- epilogue ----
  if (FFN1) {
#pragma unroll
    for (int m = 0; m < 4; m++)
#pragma unroll
      for (int cc = 0; cc < 2; cc++) {
        f32x4 v1 = acc[m][cc], v3 = acc[m][cc + 2];
        int col = nt * 64 + wcn * 32 + cc * 16 + (lane & 15);
#pragma unroll
        for (int i = 0; i < 4; i++) {
          int row = m0 + wr * 64 + m * 16 + ((lane >> 4) * 4) + i;
          if (row < cnt_e) {
            float a1v = v1[i];
            float hv = (a1v / (1.f + __expf(-a1v))) * v3[i];
            outp[(size_t)(bse + row) * DE + col] = (short)f2bf(hv);
          }
        }
      }
  } else {
#pragma unroll
    for (int m = 0; m < 4; m++)
#pragma unroll
      for (int n = 0; n < 4; n++) {
        f32x4 v = acc[m][n];
        int col = n0 + wcn * 64 + n * 16 + (lane & 15);
#pragma unroll
        for (int i = 0; i < 4; i++) {
          int row = m0 + wr * 64 + m * 16 + ((lane >> 4) * 4) + i;
          if (row < cnt_e)
            outp[(size_t)(bse + row) * DM + col] = (short)f2bf(v[i]);
        }
      }
  }
}

// ------- combine: out[t] = w0*y[s0] + w1*y[s1]; 2 tokens/block, 16B loads -------
__global__ __launch_bounds__(256) void k_combine(const short* __restrict__ y,
                                                 const int* __restrict__ slot_of_tok,
                                                 const float* __restrict__ wgt,
                                                 float* __restrict__ out) {
  int t = blockIdx.x * 2 + (threadIdx.x >> 7);
  int tt = threadIdx.x & 127;
  int s0 = slot_of_tok[2 * t], s1 = slot_of_tok[2 * t + 1];
  float w0 = wgt[2 * t], w1 = wgt[2 * t + 1];
  int c = tt * 8;
  short8 a = *(const short8*)(y + (size_t)s0 * DM + c);
  short8 b = *(const short8*)(y + (size_t)s1 * DM + c);
  f32x4 o0, o1;
#pragma unroll
  for (int j = 0; j < 4; j++) {
    o0[j] = w0 * bf2f((unsigned short)a[j]) + w1 * bf2f((unsigned short)b[j]);
    o1[j] = w0 * bf2f((unsigned short)a[j + 4]) + w1 * bf2f((unsigned short)b[j + 4]);
  }
  *(f32x4*)(out + (size_t)t * DM + c) = o0;
  *(f32x4*)(out + (size_t)t * DM + c + 4) = o1;
}

extern "C" void kernel_launch(void* const* d_in, const int* in_sizes, int n_in,
                              void* d_out, int out_size, void* d_ws, size_t ws_size,
                              hipStream_t stream) {
  const float* x  = (const float*)d_in[0];
  const float* Wr = (const float*)d_in[1];
  const float* W1 = (const float*)d_in[2];
  const float* W2 = (const float*)d_in[3];
  const float* W3 = (const float*)d_in[4];
  float* out = (float*)d_out;
  char* ws = (char*)d_ws;

  short* xb   = (short*)(ws);                   // 16 MB
  short* wcat = (short*)(ws + 16777216);        // 32 MB (8 x 2048 x 1024 bf16)
  short* w2t  = (short*)(ws + 50331648);        // 16 MB
  short* h    = (short*)(ws + 67108864);        // 32 MB
  short* y    = (short*)(ws + 100663296);       // 32 MB
  char* meta = ws + 134217728;
  int* cnt          = (int*)(meta);
  int* esel         = (int*)(meta + 512);
  int* rank         = (int*)(meta + 512 + 65536);
  int* tok_of_slot  = (int*)(meta + 512 + 2 * 65536);
  int* slot_of_tok  = (int*)(meta + 512 + 3 * 65536);
  float* wgt        = (float*)(meta + 512 + 4 * 65536);

  hipMemsetAsync(cnt, 0, 32, stream);
  k_transw<<<dim3(16, 16, 24), 256, 0, stream>>>(W1, W2, W3, wcat, w2t);
  k_router<<<2048, 256, 0, stream>>>(x, Wr, xb, esel, wgt);
  k_rank<<<32, 256, 0, stream>>>(esel, cnt, rank);
  k_scatter<<<32, 256, 0, stream>>>(cnt, esel, rank, tok_of_slot, slot_of_tok);
  k_ffn<1><<<dim3(32 * 8 * 16), 512, 0, stream>>>(xb, wcat, cnt, tok_of_slot, h);
  k_ffn<0><<<dim3(32 * 8 * 8), 512, 0, stream>>>(h, w2t, cnt, tok_of_slot, y);
  k_combine<<<4096, 256, 0, stream>>>(y, slot_of_tok, wgt, out);
}

// Round 12
// 228.935 us; speedup vs baseline: 1.1872x; 1.0329x over previous
//
#include <hip/hip_runtime.h>
#include <hip/hip_bf16.h>

typedef __attribute__((ext_vector_type(8))) short short8;
typedef __attribute__((ext_vector_type(4))) short short4v;
typedef __attribute__((ext_vector_type(4))) unsigned short ushort4v;
typedef __attribute__((ext_vector_type(4))) float f32x4;

#define NTOK 8192
#define DM 1024
#define DE 1024
#define NE 8

__device__ __forceinline__ float bf2f(unsigned short u) {
  union { unsigned int i; float f; } v; v.i = ((unsigned int)u) << 16; return v.f;
}
__device__ __forceinline__ unsigned short f2bf(float f) {
  union { float f; unsigned int i; } v; v.f = f;
  unsigned int lsb = (v.i >> 16) & 1;
  v.i += 0x7fffu + lsb;  // RNE; inputs finite
  return (unsigned short)(v.i >> 16);
}
__device__ __forceinline__ void gl_lds(const short* g, short* l) {
  __builtin_amdgcn_global_load_lds((const __attribute__((address_space(1))) void*)g,
                                   (__attribute__((address_space(3))) void*)l, 16, 0, 0);
}

// ==== fused prep: blocks 0..2047 = router; 2048..8191 = weight transpose ====
// Router (x,Wr) and transw (W1/W2/W3) are independent -> one dispatch overlaps
// router's ~8us under transw's memory-bound ~24us and drops a launch gap.
// wcat[e]: 2048 rows in 128-row groups: group g rows [g*128, g*128+64) = W1^T
//          cols g*64+[0,64); rows +64 = W3^T same cols.
// w2t[e]: plain W2^T [1024][1024]
__global__ __launch_bounds__(256) void k_prep(const float* __restrict__ W1,
                                              const float* __restrict__ W2,
                                              const float* __restrict__ W3,
                                              const float* __restrict__ x,
                                              const float* __restrict__ Wr,
                                              short* __restrict__ wcat,
                                              short* __restrict__ w2t,
                                              short* __restrict__ xb,
                                              int* __restrict__ esel,
                                              float* __restrict__ wgt) {
  const int b = blockIdx.x;
  if (b < 2048) {
    // ---------------- router: fp32 logits, softmax-top2, x->bf16 ----------------
    int wid = threadIdx.x >> 6, lane = threadIdx.x & 63;
    int t = b * 4 + wid;
    const float* xr = x + (size_t)t * DM;
    float acc[8];
#pragma unroll
    for (int e = 0; e < 8; e++) acc[e] = 0.f;
#pragma unroll
    for (int i = 0; i < 4; i++) {
      int kb = (i * 64 + lane) * 4;
      f32x4 v = *(const f32x4*)(xr + kb);
      ushort4v ob;
#pragma unroll
      for (int j = 0; j < 4; j++) {
        f32x4 w0 = *(const f32x4*)(Wr + (size_t)(kb + j) * 8);
        f32x4 w1 = *(const f32x4*)(Wr + (size_t)(kb + j) * 8 + 4);
        float xv = v[j];
        ob[j] = f2bf(xv);
        acc[0] += xv * w0[0]; acc[1] += xv * w0[1];
        acc[2] += xv * w0[2]; acc[3] += xv * w0[3];
        acc[4] += xv * w1[0]; acc[5] += xv * w1[1];
        acc[6] += xv * w1[2]; acc[7] += xv * w1[3];
      }
      *(ushort4v*)(xb + (size_t)t * DM + kb) = ob;
    }
#pragma unroll
    for (int off = 32; off; off >>= 1)
#pragma unroll
      for (int e = 0; e < 8; e++) acc[e] += __shfl_xor(acc[e], off);
    float m0 = -1e30f, m1 = -1e30f; int e0 = 0, e1 = 0;
#pragma unroll
    for (int e = 0; e < 8; e++) {
      float v = acc[e];
      if (v > m0) { m1 = m0; e1 = e0; m0 = v; e0 = e; }
      else if (v > m1) { m1 = v; e1 = e; }
    }
    float p = __expf(m1 - m0);
    if (lane == 0) {
      esel[2 * t] = e0; esel[2 * t + 1] = e1;
      wgt[2 * t] = 1.f / (1.f + p); wgt[2 * t + 1] = p / (1.f + p);
    }
    return;
  }
  // ---------------- transw: W fp32 [K][N] -> bf16 transposed ----------------
  __shared__ float t[64][65];
  const int bb = b - 2048;
  const int mid = bb >> 8;            // 0..23
  const int rem = bb & 255;
  const int by = rem >> 4, bx = rem & 15;
  const float* src;
  if (mid < 8)       src = W1 + (size_t)mid * (DM * DE);
  else if (mid < 16) src = W3 + (size_t)(mid - 8) * (DM * DE);
  else               src = W2 + (size_t)(mid - 16) * (DE * DM);
  int tid = threadIdx.x;
  int tr = tid >> 4, tc = tid & 15;
  int kbase = by * 64, nbase = bx * 64;
#pragma unroll
  for (int j = 0; j < 4; j++) {
    int kr = tr + j * 16;
    f32x4 v = *(const f32x4*)(src + (size_t)(kbase + kr) * 1024 + nbase + tc * 4);
    t[kr][tc * 4 + 0] = v[0]; t[kr][tc * 4 + 1] = v[1];
    t[kr][tc * 4 + 2] = v[2]; t[kr][tc * 4 + 3] = v[3];
  }
  __syncthreads();
#pragma unroll
  for (int j = 0; j < 4; j++) {
    int n = tr + j * 16;          // source column (0..1023 within this matrix)
    int ng = nbase + n;
    short4v o;
    o[0] = (short)f2bf(t[tc * 4 + 0][n]);
    o[1] = (short)f2bf(t[tc * 4 + 1][n]);
    o[2] = (short)f2bf(t[tc * 4 + 2][n]);
    o[3] = (short)f2bf(t[tc * 4 + 3][n]);
    size_t dsto;
    if (mid < 16) {
      int e = mid & 7, p = mid >> 3;
      int row_out = ((ng >> 6) * 128) + p * 64 + (ng & 63);
      dsto = (size_t)e * (2048 * 1024) + (size_t)row_out * 1024 + kbase + tc * 4;
      *(short4v*)(wcat + dsto) = o;
    } else {
      int e = mid - 16;
      dsto = (size_t)e * (1024 * 1024) + (size_t)ng * 1024 + kbase + tc * 4;
      *(short4v*)(w2t + dsto) = o;
    }
  }
}

// ---- ranks via wave ballots + per-block aggregated atomics ----
__global__ __launch_bounds__(256) void k_rank(const int* __restrict__ esel,
                                              int* __restrict__ cnt,
                                              int* __restrict__ rank) {
  __shared__ int wcnt[4][8];
  __shared__ int woff[4][8];
  int tid = threadIdx.x;
  int lane = tid & 63, wid = tid >> 6;
  int t = blockIdx.x * 256 + tid;
  int e0 = esel[2 * t], e1 = esel[2 * t + 1];
  unsigned long long lt = (lane == 0) ? 0ull : ((~0ull) >> (64 - lane));
  int r0 = 0, r1 = 0;
#pragma unroll
  for (int e = 0; e < 8; e++) {
    unsigned long long m0 = __ballot(e0 == e);
    unsigned long long m1 = __ballot(e1 == e);
    int c0 = __popcll(m0);
    if (e0 == e) r0 = __popcll(m0 & lt);
    if (e1 == e) r1 = c0 + __popcll(m1 & lt);
    if (lane == 0) wcnt[wid][e] = c0 + __popcll(m1);
  }
  __syncthreads();
  if (tid < 8) {
    int e = tid;
    int c0 = wcnt[0][e], c1 = wcnt[1][e], c2 = wcnt[2][e], c3 = wcnt[3][e];
    int base = atomicAdd(&cnt[e], c0 + c1 + c2 + c3);
    woff[0][e] = base;
    woff[1][e] = base + c0;
    woff[2][e] = base + c0 + c1;
    woff[3][e] = base + c0 + c1 + c2;
  }
  __syncthreads();
  rank[2 * t] = woff[wid][e0] + r0;
  rank[2 * t + 1] = woff[wid][e1] + r1;
}

// ---- scatter: prefix computed inline from cnt ----
__global__ __launch_bounds__(256) void k_scatter(const int* __restrict__ cnt,
                                                 const int* __restrict__ esel,
                                                 const int* __restrict__ rank,
                                                 int* __restrict__ tok_of_slot,
                                                 int* __restrict__ slot_of_tok) {
  int t = blockIdx.x * 256 + threadIdx.x;
#pragma unroll
  for (int j = 0; j < 2; j++) {
    int e = esel[2 * t + j];
    int base = 0;
#pragma unroll
    for (int i = 0; i < NE; i++) base += (i < e) ? cnt[i] : 0;
    int s = base + rank[2 * t + j];
    tok_of_slot[s] = t;
    slot_of_tok[2 * t + j] = s;
  }
}

// ============ 256x128-tile BK=32 grouped GEMM, 3-ring counted-vmcnt ============
// R3/R11 (best measured): R1 inner loop (0-conflict 16x16x32 fragment reads,
// 2 barriers/tile, 2 blocks/CU) + expert-per-XCD remap:
//   flat grid; lid -> bijective chunked swizzle: XCD c = lid&7 processes
//   expert c only, panels (ntile) sequential, mtile fastest. B-panel fetched
//   once per XCD then L2-hit; A-gather rows XCD-local with 16x reuse; FFN2
//   reads h written by the same XCD. (FETCH 82 MB, lowest of 11 mappings.)
// bse (expert slot base) computed inline from cnt.
// FFN1=1: A = xb gathered via tok_of_slot, B = wcat (128-row group = 64 W1 +
//         64 W3 col pairs), epilogue silu(a1)*a3 -> h (64 cols/blk)
// FFN1=0: A = h (slot rows), B = w2t, epilogue -> y (128 cols/blk)
template<int FFN1>
__global__ __launch_bounds__(512, 4) void k_ffn(const short* __restrict__ Abase,
                                                const short* __restrict__ Bbase,
                                                const int* __restrict__ cnt,
                                                const int* __restrict__ tok_of_slot,
                                                short* __restrict__ outp) {
  const int NT = FFN1 ? 16 : 8;        // ntiles per expert
  const int lid = blockIdx.x;          // flat grid: 32*8*NT blocks
  const int q = 32 * NT;               // blocks per XCD (total/8)
  const int swz = (lid & 7) * q + (lid >> 3);
  const int mt = swz & 31;
  const int pnl = swz >> 5;
  const int e = pnl / NT;              // == lid&7 : one expert per XCD
  const int nt = pnl % NT;

  const int cnt_e = cnt[e];
  const int m0 = mt * 256;
  if (m0 >= cnt_e) return;
  int bse = 0;
#pragma unroll
  for (int i = 0; i < NE; i++) bse += (i < e) ? cnt[i] : 0;
  const int n0 = nt * 128;
  const short* Bt = Bbase + (size_t)e * ((FFN1 ? 2048 : 1024) * 1024) + (size_t)n0 * 1024;

  // one k-tile: A 256x32 bf16 = 16 KB (8192 shorts), B 128x32 = 8 KB (4096)
  __shared__ __align__(128) short Al[3][8192];  // 48 KB
  __shared__ __align__(128) short Bl[3][4096];  // 24 KB  (72 KB total/block)

  const int tid = threadIdx.x;
  const int lane = tid & 63, wid = tid >> 6;
  const int wr = wid >> 1, wcn = wid & 1;

  // staging sources: chunk ch; row r = ch>>2; src col-chunk
  // c = (ch&3) ^ ((r>>1)&3)  (inverse-swizzled source, linear LDS dest)
  const short* srcA0; const short* srcA1; const short* srcB0;
  {
    int r0 = tid >> 2, c0 = (tid & 3) ^ ((r0 >> 1) & 3);
    int row0 = m0 + r0; if (row0 >= cnt_e) row0 = cnt_e - 1;
    long ar0 = FFN1 ? (long)tok_of_slot[bse + row0] : (long)(bse + row0);
    srcA0 = Abase + ar0 * 1024 + c0 * 8;
    int ch1 = tid + 512;
    int r1 = ch1 >> 2, c1 = (ch1 & 3) ^ ((r1 >> 1) & 3);
    int row1 = m0 + r1; if (row1 >= cnt_e) row1 = cnt_e - 1;
    long ar1 = FFN1 ? (long)tok_of_slot[bse + row1] : (long)(bse + row1);
    srcA1 = Abase + ar1 * 1024 + c1 * 8;
    srcB0 = Bt + (size_t)r0 * 1024 + c0 * 8;   // r0 < 128 for tid < 512
  }
  const int lA0 = wid * 512, lA1 = wid * 512 + 4096, lB0 = wid * 512;

  // fragment LDS byte offsets (swizzled read side) — proven 0-conflict pattern
  int aoff[4], boff[4];
#pragma unroll
  for (int m = 0; m < 4; m++) {
    int r = wr * 64 + m * 16 + (lane & 15);
    aoff[m] = (r * 4 + ((lane >> 4) ^ ((r >> 1) & 3))) * 16;
  }
#pragma unroll
  for (int n = 0; n < 4; n++) {
    int rb = FFN1 ? (wcn * 32 + (n & 1) * 16 + (n >> 1) * 64 + (lane & 15))
                  : (wcn * 64 + n * 16 + (lane & 15));
    boff[n] = (rb * 4 + ((lane >> 4) ^ ((rb >> 1) & 3))) * 16;
  }

  f32x4 acc[4][4];
#pragma unroll
  for (int m = 0; m < 4; m++)
#pragma unroll
    for (int n = 0; n < 4; n++) acc[m][n] = (f32x4){0.f, 0.f, 0.f, 0.f};

#define STG_A(b, kt) { gl_lds(srcA0 + (kt) * 32, &Al[b][lA0]); \
                       gl_lds(srcA1 + (kt) * 32, &Al[b][lA1]); }
#define STG_B(b, kt) { gl_lds(srcB0 + (kt) * 32, &Bl[b][lB0]); }

  // prologue: tiles 0,1 issued (3 loads each); wait tile 0 (tile 1 in flight)
  STG_A(0, 0); STG_B(0, 0);
  STG_A(1, 1); STG_B(1, 1);
  asm volatile("s_waitcnt vmcnt(3)" ::: "memory");
  __builtin_amdgcn_s_barrier();

  int cur = 0, nxt = 2;
  for (int t = 0; t < 32; ++t) {
    int ktn = (t + 2 < 32) ? (t + 2) : 31;  // clamped dup-stage: same bytes, benign
    const char* Ab = (const char*)Al[cur];
    const char* Bb = (const char*)Bl[cur];
    short8 a[4], b[4];
#pragma unroll
    for (int m = 0; m < 4; m++) a[m] = *(const short8*)(Ab + aoff[m]);
#pragma unroll
    for (int n = 0; n < 4; n++) b[n] = *(const short8*)(Bb + boff[n]);
    STG_A(nxt, ktn); STG_B(nxt, ktn);
    __builtin_amdgcn_s_barrier();
    __builtin_amdgcn_s_setprio(1);
#pragma unroll
    for (int m = 0; m < 4; m++)
#pragma unroll
      for (int n = 0; n < 4; n++)
        acc[m][n] = __builtin_amdgcn_mfma_f32_16x16x32_bf16(a[m], b[n], acc[m][n], 0, 0, 0);
    __builtin_amdgcn_s_setprio(0);
    asm volatile("s_waitcnt vmcnt(3)" ::: "memory");  // tile t+1 arrived; t+2 in flight
    __builtin_amdgcn_s_barrier();
    cur = (cur == 2) ? 0 : cur + 1;
    nxt = (nxt == 2) ? 0 : nxt + 1;
  }
  asm volatile("s_waitcnt vmcnt(0)" ::: "memory");  // drain before LDS dealloc

  // ---- epilogue ----
  if (FFN1) {
#pragma unroll
    for (int m = 0; m < 4; m++)
#pragma unroll
      for (int cc = 0; cc < 2; cc++) {
        f32x4 v1 = acc[m][cc], v3 = acc[m][cc + 2];
        int col = nt * 64 + wcn * 32 + cc * 16 + (lane & 15);
#pragma unroll
        for (int i = 0; i < 4; i++) {
          int row = m0 + wr * 64 + m * 16 + ((lane >> 4) * 4) + i;
          if (row < cnt_e) {
            float a1v = v1[i];
            float hv = (a1v / (1.f + __expf(-a1v))) * v3[i];
            outp[(size_t)(bse + row) * DE + col] = (short)f2bf(hv);
          }
        }
      }
  } else {
#pragma unroll
    for (int m = 0; m < 4; m++)
#pragma unroll
      for (int n = 0; n < 4; n++) {
        f32x4 v = acc[m][n];
        int col = n0 + wcn * 64 + n * 16 + (lane & 15);
#pragma unroll
        for (int i = 0; i < 4; i++) {
          int row = m0 + wr * 64 + m * 16 + ((lane >> 4) * 4) + i;
          if (row < cnt_e)
            outp[(size_t)(bse + row) * DM + col] = (short)f2bf(v[i]);
        }
      }
  }
}

// ------- combine: out[t] = w0*y[s0] + w1*y[s1]; 2 tokens/block, 16B loads -------
__global__ __launch_bounds__(256) void k_combine(const short* __restrict__ y,
                                                 const int* __restrict__ slot_of_tok,
                                                 const float* __restrict__ wgt,
                                                 float* __restrict__ out) {
  int t = blockIdx.x * 2 + (threadIdx.x >> 7);
  int tt = threadIdx.x & 127;
  int s0 = slot_of_tok[2 * t], s1 = slot_of_tok[2 * t + 1];
  float w0 = wgt[2 * t], w1 = wgt[2 * t + 1];
  int c = tt * 8;
  short8 a = *(const short8*)(y + (size_t)s0 * DM + c);
  short8 b = *(const short8*)(y + (size_t)s1 * DM + c);
  f32x4 o0, o1;
#pragma unroll
  for (int j = 0; j < 4; j++) {
    o0[j] = w0 * bf2f((unsigned short)a[j]) + w1 * bf2f((unsigned short)b[j]);
    o1[j] = w0 * bf2f((unsigned short)a[j + 4]) + w1 * bf2f((unsigned short)b[j + 4]);
  }
  *(f32x4*)(out + (size_t)t * DM + c) = o0;
  *(f32x4*)(out + (size_t)t * DM + c + 4) = o1;
}

extern "C" void kernel_launch(void* const* d_in, const int* in_sizes, int n_in,
                              void* d_out, int out_size, void* d_ws, size_t ws_size,
                              hipStream_t stream) {
  const float* x  = (const float*)d_in[0];
  const float* Wr = (const float*)d_in[1];
  const float* W1 = (const float*)d_in[2];
  const float* W2 = (const float*)d_in[3];
  const float* W3 = (const float*)d_in[4];
  float* out = (float*)d_out;
  char* ws = (char*)d_ws;

  short* xb   = (short*)(ws);                   // 16 MB
  short* wcat = (short*)(ws + 16777216);        // 32 MB (8 x 2048 x 1024 bf16)
  short* w2t  = (short*)(ws + 50331648);        // 16 MB
  short* h    = (short*)(ws + 67108864);        // 32 MB
  short* y    = (short*)(ws + 100663296);       // 32 MB
  char* meta = ws + 134217728;
  int* cnt          = (int*)(meta);
  int* esel         = (int*)(meta + 512);
  int* rank         = (int*)(meta + 512 + 65536);
  int* tok_of_slot  = (int*)(meta + 512 + 2 * 65536);
  int* slot_of_tok  = (int*)(meta + 512 + 3 * 65536);
  float* wgt        = (float*)(meta + 512 + 4 * 65536);

  hipMemsetAsync(cnt, 0, 32, stream);
  k_prep<<<8192, 256, 0, stream>>>(W1, W2, W3, x, Wr, wcat, w2t, xb, esel, wgt);
  k_rank<<<32, 256, 0, stream>>>(esel, cnt, rank);
  k_scatter<<<32, 256, 0, stream>>>(cnt, esel, rank, tok_of_slot, slot_of_tok);
  k_ffn<1><<<dim3(32 * 8 * 16), 512, 0, stream>>>(xb, wcat, cnt, tok_of_slot, h);
  k_ffn<0><<<dim3(32 * 8 * 8), 512, 0, stream>>>(h, w2t, cnt, tok_of_slot, y);
  k_combine<<<4096, 256, 0, stream>>>(y, slot_of_tok, wgt, out);
}

// Round 13
// 226.171 us; speedup vs baseline: 1.2017x; 1.0122x over previous
//
#include <hip/hip_runtime.h>
#include <hip/hip_bf16.h>

typedef __attribute__((ext_vector_type(8))) short short8;
typedef __attribute__((ext_vector_type(4))) short short4v;
typedef __attribute__((ext_vector_type(4))) unsigned short ushort4v;
typedef __attribute__((ext_vector_type(4))) float f32x4;

#define NTOK 8192
#define DM 1024
#define DE 1024
#define NE 8

__device__ __forceinline__ float bf2f(unsigned short u) {
  union { unsigned int i; float f; } v; v.i = ((unsigned int)u) << 16; return v.f;
}
__device__ __forceinline__ unsigned short f2bf(float f) {
  union { float f; unsigned int i; } v; v.f = f;
  unsigned int lsb = (v.i >> 16) & 1;
  v.i += 0x7fffu + lsb;  // RNE; inputs finite
  return (unsigned short)(v.i >> 16);
}
__device__ __forceinline__ void gl_lds(const short* g, short* l) {
  __builtin_amdgcn_global_load_lds((const __attribute__((address_space(1))) void*)g,
                                   (__attribute__((address_space(3))) void*)l, 16, 0, 0);
}

// ==== fused prep: blocks 0..2047 = router; 2048..8191 = weight transpose ====
// wcat[e]: 2048 rows in 128-row groups: group g rows [g*128, g*128+64) = W1^T
//          cols g*64+[0,64); rows +64 = W3^T same cols.
// w2t[e]: plain W2^T [1024][1024]
__global__ __launch_bounds__(256) void k_prep(const float* __restrict__ W1,
                                              const float* __restrict__ W2,
                                              const float* __restrict__ W3,
                                              const float* __restrict__ x,
                                              const float* __restrict__ Wr,
                                              short* __restrict__ wcat,
                                              short* __restrict__ w2t,
                                              short* __restrict__ xb,
                                              int* __restrict__ esel,
                                              float* __restrict__ wgt) {
  const int b = blockIdx.x;
  if (b < 2048) {
    // ---------------- router: fp32 logits, softmax-top2, x->bf16 ----------------
    int wid = threadIdx.x >> 6, lane = threadIdx.x & 63;
    int t = b * 4 + wid;
    const float* xr = x + (size_t)t * DM;
    float acc[8];
#pragma unroll
    for (int e = 0; e < 8; e++) acc[e] = 0.f;
#pragma unroll
    for (int i = 0; i < 4; i++) {
      int kb = (i * 64 + lane) * 4;
      f32x4 v = *(const f32x4*)(xr + kb);
      ushort4v ob;
#pragma unroll
      for (int j = 0; j < 4; j++) {
        f32x4 w0 = *(const f32x4*)(Wr + (size_t)(kb + j) * 8);
        f32x4 w1 = *(const f32x4*)(Wr + (size_t)(kb + j) * 8 + 4);
        float xv = v[j];
        ob[j] = f2bf(xv);
        acc[0] += xv * w0[0]; acc[1] += xv * w0[1];
        acc[2] += xv * w0[2]; acc[3] += xv * w0[3];
        acc[4] += xv * w1[0]; acc[5] += xv * w1[1];
        acc[6] += xv * w1[2]; acc[7] += xv * w1[3];
      }
      *(ushort4v*)(xb + (size_t)t * DM + kb) = ob;
    }
#pragma unroll
    for (int off = 32; off; off >>= 1)
#pragma unroll
      for (int e = 0; e < 8; e++) acc[e] += __shfl_xor(acc[e], off);
    float m0 = -1e30f, m1 = -1e30f; int e0 = 0, e1 = 0;
#pragma unroll
    for (int e = 0; e < 8; e++) {
      float v = acc[e];
      if (v > m0) { m1 = m0; e1 = e0; m0 = v; e0 = e; }
      else if (v > m1) { m1 = v; e1 = e; }
    }
    float p = __expf(m1 - m0);
    if (lane == 0) {
      esel[2 * t] = e0; esel[2 * t + 1] = e1;
      wgt[2 * t] = 1.f / (1.f + p); wgt[2 * t + 1] = p / (1.f + p);
    }
    return;
  }
  // ---------------- transw: W fp32 [K][N] -> bf16 transposed ----------------
  __shared__ float t[64][65];
  const int bb = b - 2048;
  const int mid = bb >> 8;            // 0..23
  const int rem = bb & 255;
  const int by = rem >> 4, bx = rem & 15;
  const float* src;
  if (mid < 8)       src = W1 + (size_t)mid * (DM * DE);
  else if (mid < 16) src = W3 + (size_t)(mid - 8) * (DM * DE);
  else               src = W2 + (size_t)(mid - 16) * (DE * DM);
  int tid = threadIdx.x;
  int tr = tid >> 4, tc = tid & 15;
  int kbase = by * 64, nbase = bx * 64;
#pragma unroll
  for (int j = 0; j < 4; j++) {
    int kr = tr + j * 16;
    f32x4 v = *(const f32x4*)(src + (size_t)(kbase + kr) * 1024 + nbase + tc * 4);
    t[kr][tc * 4 + 0] = v[0]; t[kr][tc * 4 + 1] = v[1];
    t[kr][tc * 4 + 2] = v[2]; t[kr][tc * 4 + 3] = v[3];
  }
  __syncthreads();
#pragma unroll
  for (int j = 0; j < 4; j++) {
    int n = tr + j * 16;          // source column (0..1023 within this matrix)
    int ng = nbase + n;
    short4v o;
    o[0] = (short)f2bf(t[tc * 4 + 0][n]);
    o[1] = (short)f2bf(t[tc * 4 + 1][n]);
    o[2] = (short)f2bf(t[tc * 4 + 2][n]);
    o[3] = (short)f2bf(t[tc * 4 + 3][n]);
    size_t dsto;
    if (mid < 16) {
      int e = mid & 7, p = mid >> 3;
      int row_out = ((ng >> 6) * 128) + p * 64 + (ng & 63);
      dsto = (size_t)e * (2048 * 1024) + (size_t)row_out * 1024 + kbase + tc * 4;
      *(short4v*)(wcat + dsto) = o;
    } else {
      int e = mid - 16;
      dsto = (size_t)e * (1024 * 1024) + (size_t)ng * 1024 + kbase + tc * 4;
      *(short4v*)(w2t + dsto) = o;
    }
  }
}

// ---- ranks via wave ballots + per-block aggregated atomics ----
__global__ __launch_bounds__(256) void k_rank(const int* __restrict__ esel,
                                              int* __restrict__ cnt,
                                              int* __restrict__ rank) {
  __shared__ int wcnt[4][8];
  __shared__ int woff[4][8];
  int tid = threadIdx.x;
  int lane = tid & 63, wid = tid >> 6;
  int t = blockIdx.x * 256 + tid;
  int e0 = esel[2 * t], e1 = esel[2 * t + 1];
  unsigned long long lt = (lane == 0) ? 0ull : ((~0ull) >> (64 - lane));
  int r0 = 0, r1 = 0;
#pragma unroll
  for (int e = 0; e < 8; e++) {
    unsigned long long m0 = __ballot(e0 == e);
    unsigned long long m1 = __ballot(e1 == e);
    int c0 = __popcll(m0);
    if (e0 == e) r0 = __popcll(m0 & lt);
    if (e1 == e) r1 = c0 + __popcll(m1 & lt);
    if (lane == 0) wcnt[wid][e] = c0 + __popcll(m1);
  }
  __syncthreads();
  if (tid < 8) {
    int e = tid;
    int c0 = wcnt[0][e], c1 = wcnt[1][e], c2 = wcnt[2][e], c3 = wcnt[3][e];
    int base = atomicAdd(&cnt[e], c0 + c1 + c2 + c3);
    woff[0][e] = base;
    woff[1][e] = base + c0;
    woff[2][e] = base + c0 + c1;
    woff[3][e] = base + c0 + c1 + c2;
  }
  __syncthreads();
  rank[2 * t] = woff[wid][e0] + r0;
  rank[2 * t + 1] = woff[wid][e1] + r1;
}

// ---- scatter: prefix computed inline from cnt ----
__global__ __launch_bounds__(256) void k_scatter(const int* __restrict__ cnt,
                                                 const int* __restrict__ esel,
                                                 const int* __restrict__ rank,
                                                 int* __restrict__ tok_of_slot,
                                                 int* __restrict__ slot_of_tok) {
  int t = blockIdx.x * 256 + threadIdx.x;
#pragma unroll
  for (int j = 0; j < 2; j++) {
    int e = esel[2 * t + j];
    int base = 0;
#pragma unroll
    for (int i = 0; i < NE; i++) base += (i < e) ? cnt[i] : 0;
    int s = base + rank[2 * t + j];
    tok_of_slot[s] = t;
    slot_of_tok[2 * t + j] = s;
  }
}

// ============ FFN1: 256x128-tile BK=32 grouped GEMM (R3/R12 verbatim) ============
// R1 inner loop (0-conflict 16x16x32 fragment reads, 2 barriers/tile,
// 2 blocks/CU) + expert-per-XCD remap (FETCH 82 MB, lowest of 11 mappings).
// A = xb gathered via tok_of_slot, B = wcat (128-row group = 64 W1 + 64 W3
// col pairs), epilogue silu(a1)*a3 -> h (64 cols/blk)
__global__ __launch_bounds__(512, 4) void k_ffn1(const short* __restrict__ Abase,
                                                 const short* __restrict__ Bbase,
                                                 const int* __restrict__ cnt,
                                                 const int* __restrict__ tok_of_slot,
                                                 short* __restrict__ outp) {
  const int NT = 16;                   // ntiles per expert
  const int lid = blockIdx.x;          // flat grid: 32*8*NT blocks
  const int q = 32 * NT;               // blocks per XCD (total/8)
  const int swz = (lid & 7) * q + (lid >> 3);
  const int mt = swz & 31;
  const int pnl = swz >> 5;
  const int e = pnl / NT;              // == lid&7 : one expert per XCD
  const int nt = pnl % NT;

  const int cnt_e = cnt[e];
  const int m0 = mt * 256;
  if (m0 >= cnt_e) return;
  int bse = 0;
#pragma unroll
  for (int i = 0; i < NE; i++) bse += (i < e) ? cnt[i] : 0;
  const int n0 = nt * 128;
  const short* Bt = Bbase + (size_t)e * (2048 * 1024) + (size_t)n0 * 1024;

  __shared__ __align__(128) short Al[3][8192];  // 48 KB
  __shared__ __align__(128) short Bl[3][4096];  // 24 KB  (72 KB total/block)

  const int tid = threadIdx.x;
  const int lane = tid & 63, wid = tid >> 6;
  const int wr = wid >> 1, wcn = wid & 1;

  const short* srcA0; const short* srcA1; const short* srcB0;
  {
    int r0 = tid >> 2, c0 = (tid & 3) ^ ((r0 >> 1) & 3);
    int row0 = m0 + r0; if (row0 >= cnt_e) row0 = cnt_e - 1;
    long ar0 = (long)tok_of_slot[bse + row0];
    srcA0 = Abase + ar0 * 1024 + c0 * 8;
    int ch1 = tid + 512;
    int r1 = ch1 >> 2, c1 = (ch1 & 3) ^ ((r1 >> 1) & 3);
    int row1 = m0 + r1; if (row1 >= cnt_e) row1 = cnt_e - 1;
    long ar1 = (long)tok_of_slot[bse + row1];
    srcA1 = Abase + ar1 * 1024 + c1 * 8;
    srcB0 = Bt + (size_t)r0 * 1024 + c0 * 8;   // r0 < 128 for tid < 512
  }
  const int lA0 = wid * 512, lA1 = wid * 512 + 4096, lB0 = wid * 512;

  int aoff[4], boff[4];
#pragma unroll
  for (int m = 0; m < 4; m++) {
    int r = wr * 64 + m * 16 + (lane & 15);
    aoff[m] = (r * 4 + ((lane >> 4) ^ ((r >> 1) & 3))) * 16;
  }
#pragma unroll
  for (int n = 0; n < 4; n++) {
    int rb = wcn * 32 + (n & 1) * 16 + (n >> 1) * 64 + (lane & 15);
    boff[n] = (rb * 4 + ((lane >> 4) ^ ((rb >> 1) & 3))) * 16;
  }

  f32x4 acc[4][4];
#pragma unroll
  for (int m = 0; m < 4; m++)
#pragma unroll
    for (int n = 0; n < 4; n++) acc[m][n] = (f32x4){0.f, 0.f, 0.f, 0.f};

#define STG_A(b, kt) { gl_lds(srcA0 + (kt) * 32, &Al[b][lA0]); \
                       gl_lds(srcA1 + (kt) * 32, &Al[b][lA1]); }
#define STG_B(b, kt) { gl_lds(srcB0 + (kt) * 32, &Bl[b][lB0]); }

  STG_A(0, 0); STG_B(0, 0);
  STG_A(1, 1); STG_B(1, 1);
  asm volatile("s_waitcnt vmcnt(3)" ::: "memory");
  __builtin_amdgcn_s_barrier();

  int cur = 0, nxt = 2;
  for (int t = 0; t < 32; ++t) {
    int ktn = (t + 2 < 32) ? (t + 2) : 31;  // clamped dup-stage: benign
    const char* Ab = (const char*)Al[cur];
    const char* Bb = (const char*)Bl[cur];
    short8 a[4], b[4];
#pragma unroll
    for (int m = 0; m < 4; m++) a[m] = *(const short8*)(Ab + aoff[m]);
#pragma unroll
    for (int n = 0; n < 4; n++) b[n] = *(const short8*)(Bb + boff[n]);
    STG_A(nxt, ktn); STG_B(nxt, ktn);
    __builtin_amdgcn_s_barrier();
    __builtin_amdgcn_s_setprio(1);
#pragma unroll
    for (int m = 0; m < 4; m++)
#pragma unroll
      for (int n = 0; n < 4; n++)
        acc[m][n] = __builtin_amdgcn_mfma_f32_16x16x32_bf16(a[m], b[n], acc[m][n], 0, 0, 0);
    __builtin_amdgcn_s_setprio(0);
    asm volatile("s_waitcnt vmcnt(3)" ::: "memory");
    __builtin_amdgcn_s_barrier();
    cur = (cur == 2) ? 0 : cur + 1;
    nxt = (nxt == 2) ? 0 : nxt + 1;
  }
  asm volatile("s_waitcnt vmcnt(0)" ::: "memory");

#pragma unroll
  for (int m = 0; m < 4; m++)
#pragma unroll
    for (int cc = 0; cc < 2; cc++) {
      f32x4 v1 = acc[m][cc], v3 = acc[m][cc + 2];
      int col = nt * 64 + wcn * 32 + cc * 16 + (lane & 15);
#pragma unroll
      for (int i = 0; i < 4; i++) {
        int row = m0 + wr * 64 + m * 16 + ((lane >> 4) * 4) + i;
        if (row < cnt_e) {
          float a1v = v1[i];
          float hv = (a1v / (1.f + __expf(-a1v))) * v3[i];
          outp[(size_t)(bse + row) * DE + col] = (short)f2bf(hv);
        }
      }
    }
}

// ====== FFN2: 128x128-tile BK=32, 4-wave, 3 blocks/CU (tail-quantization fix) ======
// FFN2's makespan was 2x a block-generation: per XCD, active blocks = 8 x
// ceil(cnt_e/256) = 64 or 72 vs 64 resident slots -> the 8 overflow blocks ran
// a nearly-idle second generation (~94 us for half FFN1's FLOPs). Fix:
// quarter-size blocks (128x128, T~23us) at 3 blocks/CU (LDS 48KB x3 = 144KB,
// launch_bounds(256,3) -> 170 regs, acc 64 + ~60 arch fits): per XCD ~136
// active over 96 slots -> makespan ~1.4T + short tail. Same proven 0-conflict
// fragment pattern (R1 64x64 wave tile), same 3-ring counted-vmcnt loop
// (4 stage-ops/tile -> vmcnt(4)), same expert-per-XCD swizzle (mt cap 64).
// A = h (slot rows), B = w2t, epilogue -> y (128 cols/blk)
__global__ __launch_bounds__(256, 3) void k_ffn2(const short* __restrict__ Abase,
                                                 const short* __restrict__ Bbase,
                                                 const int* __restrict__ cnt,
                                                 short* __restrict__ outp) {
  const int lid = blockIdx.x;          // flat grid: 8 XCD x 8 nt x 64 mt = 4096
  const int q = 512;                   // blocks per XCD
  const int swz = (lid & 7) * q + (lid >> 3);
  const int mt = swz & 63;
  const int pnl = swz >> 6;
  const int e = pnl >> 3;              // == lid&7 : one expert per XCD
  const int nt = pnl & 7;

  const int cnt_e = cnt[e];
  const int m0 = mt * 128;
  if (m0 >= cnt_e) return;
  int bse = 0;
#pragma unroll
  for (int i = 0; i < NE; i++) bse += (i < e) ? cnt[i] : 0;
  const int n0 = nt * 128;
  const short* Bt = Bbase + (size_t)e * (1024 * 1024) + (size_t)n0 * 1024;

  // k-tile: A 128x32 = 8 KB (4096 shorts), B 128x32 = 8 KB
  __shared__ __align__(128) short Al[3][4096];  // 24 KB
  __shared__ __align__(128) short Bl[3][4096];  // 24 KB (48 KB total)

  const int tid = threadIdx.x;
  const int lane = tid & 63, wid = tid >> 6;   // 4 waves
  const int wr = wid >> 1, wcn = wid & 1;      // 2M x 2N, wave tile 64x64

  // staging: chunk ch = tid + i*256; row r = ch>>2; src col-chunk
  // c = (ch&3) ^ ((r>>1)&3)  (inverse-swizzled source, linear LDS dest)
  const short* srcA[2]; const short* srcB[2];
#pragma unroll
  for (int i = 0; i < 2; i++) {
    int ch = tid + i * 256;
    int r = ch >> 2, c = (ch & 3) ^ ((r >> 1) & 3);
    int row = m0 + r; if (row >= cnt_e) row = cnt_e - 1;
    srcA[i] = Abase + (size_t)(bse + row) * 1024 + c * 8;
    srcB[i] = Bt + (size_t)r * 1024 + c * 8;
  }

  // fragment LDS byte offsets (proven 0-conflict pattern)
  int aoff[4], boff[4];
#pragma unroll
  for (int m = 0; m < 4; m++) {
    int r = wr * 64 + m * 16 + (lane & 15);
    aoff[m] = (r * 4 + ((lane >> 4) ^ ((r >> 1) & 3))) * 16;
  }
#pragma unroll
  for (int n = 0; n < 4; n++) {
    int rb = wcn * 64 + n * 16 + (lane & 15);
    boff[n] = (rb * 4 + ((lane >> 4) ^ ((rb >> 1) & 3))) * 16;
  }

  f32x4 acc[4][4];
#pragma unroll
  for (int m = 0; m < 4; m++)
#pragma unroll
    for (int n = 0; n < 4; n++) acc[m][n] = (f32x4){0.f, 0.f, 0.f, 0.f};

#define STG2(b, kt) { gl_lds(srcA[0] + (kt) * 32, &Al[b][(tid + 0) * 8]); \
                      gl_lds(srcA[1] + (kt) * 32, &Al[b][(tid + 256) * 8]); \
                      gl_lds(srcB[0] + (kt) * 32, &Bl[b][(tid + 0) * 8]); \
                      gl_lds(srcB[1] + (kt) * 32, &Bl[b][(tid + 256) * 8]); }

  // prologue: tiles 0,1 issued (4 ops each); wait tile 0 (tile 1 in flight)
  STG2(0, 0); STG2(1, 1);
  asm volatile("s_waitcnt vmcnt(4)" ::: "memory");
  __builtin_amdgcn_s_barrier();

  int cur = 0, nxt = 2;
  for (int t = 0; t < 32; ++t) {
    int ktn = (t + 2 < 32) ? (t + 2) : 31;  // clamped dup-stage: benign
    const char* Ab = (const char*)Al[cur];
    const char* Bb = (const char*)Bl[cur];
    short8 a[4], b[4];
#pragma unroll
    for (int m = 0; m < 4; m++) a[m] = *(const short8*)(Ab + aoff[m]);
#pragma unroll
    for (int n = 0; n < 4; n++) b[n] = *(const short8*)(Bb + boff[n]);
    STG2(nxt, ktn);
    __builtin_amdgcn_s_barrier();
    __builtin_amdgcn_s_setprio(1);
#pragma unroll
    for (int m = 0; m < 4; m++)
#pragma unroll
      for (int n = 0; n < 4; n++)
        acc[m][n] = __builtin_amdgcn_mfma_f32_16x16x32_bf16(a[m], b[n], acc[m][n], 0, 0, 0);
    __builtin_amdgcn_s_setprio(0);
    asm volatile("s_waitcnt vmcnt(4)" ::: "memory");  // tile t+1 landed; t+2 in flight
    __builtin_amdgcn_s_barrier();
    cur = (cur == 2) ? 0 : cur + 1;
    nxt = (nxt == 2) ? 0 : nxt + 1;
  }
  asm volatile("s_waitcnt vmcnt(0)" ::: "memory");  // drain before LDS dealloc

#pragma unroll
  for (int m = 0; m < 4; m++)
#pragma unroll
    for (int n = 0; n < 4; n++) {
      f32x4 v = acc[m][n];
      int col = n0 + wcn * 64 + n * 16 + (lane & 15);
#pragma unroll
      for (int i = 0; i < 4; i++) {
        int row = m0 + wr * 64 + m * 16 + ((lane >> 4) * 4) + i;
        if (row < cnt_e)
          outp[(size_t)(bse + row) * DM + col] = (short)f2bf(v[i]);
      }
    }
}

// ------- combine: out[t] = w0*y[s0] + w1*y[s1]; 2 tokens/block, 16B loads -------
__global__ __launch_bounds__(256) void k_combine(const short* __restrict__ y,
                                                 const int* __restrict__ slot_of_tok,
                                                 const float* __restrict__ wgt,
                                                 float* __restrict__ out) {
  int t = blockIdx.x * 2 + (threadIdx.x >> 7);
  int tt = threadIdx.x & 127;
  int s0 = slot_of_tok[2 * t], s1 = slot_of_tok[2 * t + 1];
  float w0 = wgt[2 * t], w1 = wgt[2 * t + 1];
  int c = tt * 8;
  short8 a = *(const short8*)(y + (size_t)s0 * DM + c);
  short8 b = *(const short8*)(y + (size_t)s1 * DM + c);
  f32x4 o0, o1;
#pragma unroll
  for (int j = 0; j < 4; j++) {
    o0[j] = w0 * bf2f((unsigned short)a[j]) + w1 * bf2f((unsigned short)b[j]);
    o1[j] = w0 * bf2f((unsigned short)a[j + 4]) + w1 * bf2f((unsigned short)b[j + 4]);
  }
  *(f32x4*)(out + (size_t)t * DM + c) = o0;
  *(f32x4*)(out + (size_t)t * DM + c + 4) = o1;
}

extern "C" void kernel_launch(void* const* d_in, const int* in_sizes, int n_in,
                              void* d_out, int out_size, void* d_ws, size_t ws_size,
                              hipStream_t stream) {
  const float* x  = (const float*)d_in[0];
  const float* Wr = (const float*)d_in[1];
  const float* W1 = (const float*)d_in[2];
  const float* W2 = (const float*)d_in[3];
  const float* W3 = (const float*)d_in[4];
  float* out = (float*)d_out;
  char* ws = (char*)d_ws;

  short* xb   = (short*)(ws);                   // 16 MB
  short* wcat = (short*)(ws + 16777216);        // 32 MB (8 x 2048 x 1024 bf16)
  short* w2t  = (short*)(ws + 50331648);        // 16 MB
  short* h    = (short*)(ws + 67108864);        // 32 MB
  short* y    = (short*)(ws + 100663296);       // 32 MB
  char* meta = ws + 134217728;
  int* cnt          = (int*)(meta);
  int* esel         = (int*)(meta + 512);
  int* rank         = (int*)(meta + 512 + 65536);
  int* tok_of_slot  = (int*)(meta + 512 + 2 * 65536);
  int* slot_of_tok  = (int*)(meta + 512 + 3 * 65536);
  float* wgt        = (float*)(meta + 512 + 4 * 65536);

  hipMemsetAsync(cnt, 0, 32, stream);
  k_prep<<<8192, 256, 0, stream>>>(W1, W2, W3, x, Wr, wcat, w2t, xb, esel, wgt);
  k_rank<<<32, 256, 0, stream>>>(esel, cnt, rank);
  k_scatter<<<32, 256, 0, stream>>>(cnt, esel, rank, tok_of_slot, slot_of_tok);
  k_ffn1<<<dim3(32 * 8 * 16), 512, 0, stream>>>(xb, wcat, cnt, tok_of_slot, h);
  k_ffn2<<<dim3(4096), 256, 0, stream>>>(h, w2t, cnt, y);
  k_combine<<<4096, 256, 0, stream>>>(y, slot_of_tok, wgt, out);
}